// Round 3
// baseline (245.503 us; speedup 1.0000x reference)
//
#include <hip/hip_runtime.h>
#include <hip/hip_bf16.h>

// SOLD2 line matching on MI355X.
// Inputs: line_seg1 (1200,2,2) f32, line_seg2 (1200,2,2) f32,
//         desc1 (1,128,128,128) f32, desc2 (1,128,128,128) f32
// Outputs (concat float32): matches (1200,), nw (1200,20)

#define NLINES 1200
#define NS 5
#define DD 128
#define HH 128
#define WW 128
#define HW (HH*WW)
#define IMGM1 511.0f
#define GAPC 0.1f
#define NPAD 1216          // 38*32
#define PPAD (NPAD*NS)     // 6080 padded points
#define KEXT 384           // 3-term bf16 split: [hi,lo,hi] x [hi,hi,lo]
#define NCH (KEXT/32)      // 12 k-chunks of 32

typedef __attribute__((ext_vector_type(8))) short short8;
typedef __attribute__((ext_vector_type(4))) float f32x4;

__device__ __forceinline__ void async_cp16(const void* g, void* l) {
    __builtin_amdgcn_global_load_lds(
        (const __attribute__((address_space(1))) void*)g,
        (__attribute__((address_space(3))) void*)l, 16, 0, 0);
}

// fragment-major index (in shorts) for element (pt, kext):
// block = (pt>>4, kext>>5): 1024B, lane = ((kext>>3)&3)*16 + (pt&15), sub = kext&7
__device__ __forceinline__ size_t fragidx(int pt, int kext) {
    int g = pt >> 4, r = pt & 15;
    int c = kext >> 5, q = (kext >> 3) & 3;
    return ((size_t)(g * NCH + c) * 64 + q * 16 + r) * 8 + (kext & 7);
}

// ---------------- K0: transpose desc [D][H][W] -> [H*W][D] ----------------
__global__ void transpose_desc(const float* __restrict__ in, float* __restrict__ out) {
    __shared__ float t[32][33];
    int s0 = blockIdx.x * 32;          // HW dim
    int d0 = blockIdx.y * 32;          // D dim
    int c = threadIdx.x;               // 0..31
    int r0 = threadIdx.y;              // 0..7
    #pragma unroll
    for (int rr = 0; rr < 32; rr += 8) {
        int d = d0 + r0 + rr;
        t[r0 + rr][c] = in[d * HW + s0 + c];
    }
    __syncthreads();
    #pragma unroll
    for (int rr = 0; rr < 32; rr += 8) {
        int s = s0 + r0 + rr;
        out[s * DD + d0 + c] = t[c][r0 + rr];
    }
}

// ------- K1: sample points + bilinear descriptors + bf16 hi/lo split ------
__global__ void sample_kernel(const float* __restrict__ lseg,
                              const float* __restrict__ tdesc,  // [HW][D] (if use_t)
                              const float* __restrict__ desc,   // [D][H][W]
                              float* __restrict__ Dout,         // [PPAD][128]
                              float* __restrict__ valout,       // [PPAD]
                              short* __restrict__ Ef,           // frag-major ext operand
                              int arole, int use_t) {
    int wave = (blockIdx.x * blockDim.x + threadIdx.x) >> 6;
    int lane = threadIdx.x & 63;
    int pt = wave;                      // 0..PPAD-1
    if (pt >= PPAD) return;
    int line = pt / NS;
    int k = pt - line * NS;

    float sy = 0.f, sx = 0.f, ey = 0.f, ex = 0.f;
    if (line < NLINES) {
        sy = lseg[line * 4 + 0]; sx = lseg[line * 4 + 1];
        ey = lseg[line * 4 + 2]; ex = lseg[line * 4 + 3];
    }
    float dy = ey - sy, dx = ex - sx;
    float len = sqrtf(dy * dy + dx * dx);
    float ns = floorf(len * 0.125f);
    ns = fminf(fmaxf(ns, 2.0f), 5.0f);
    float kf = (float)k;
    float validf = (kf < ns) ? 1.0f : 0.0f;
    float py = sy + kf * (dy / (ns - 1.0f));
    float px = sx + kf * (dx / (ns - 1.0f));
    if (validf == 0.0f) { py = 0.0f; px = 0.0f; }

    float xn = 2.0f * px / IMGM1 - 1.0f;
    float yn = 2.0f * py / IMGM1 - 1.0f;
    float ix = ((xn + 1.0f) * (float)WW - 1.0f) * 0.5f;
    float iy = ((yn + 1.0f) * (float)HH - 1.0f) * 0.5f;
    float x0f = floorf(ix), y0f = floorf(iy);
    float wx = ix - x0f, wy = iy - y0f;
    int x0 = (int)x0f, y0 = (int)y0f;

    float w00 = (1.0f - wx) * (1.0f - wy);
    float w10 = wx * (1.0f - wy);
    float w01 = (1.0f - wx) * wy;
    float w11 = wx * wy;

    float v0 = 0.0f, v1 = 0.0f;
    int xs[4] = { x0, x0 + 1, x0,     x0 + 1 };
    int ys[4] = { y0, y0,     y0 + 1, y0 + 1 };
    float ws4[4] = { w00, w10, w01, w11 };
    #pragma unroll
    for (int c = 0; c < 4; ++c) {
        int xi = xs[c], yi = ys[c];
        float inb = (xi >= 0 && xi < WW && yi >= 0 && yi < HH) ? 1.0f : 0.0f;
        int xc = min(max(xi, 0), WW - 1);
        int yc = min(max(yi, 0), HH - 1);
        if (use_t) {
            int base = (yc * WW + xc) * DD;
            v0 += tdesc[base + lane] * inb * ws4[c];
            v1 += tdesc[base + 64 + lane] * inb * ws4[c];
        } else {
            int base = yc * WW + xc;
            v0 += desc[lane * HW + base] * inb * ws4[c];
            v1 += desc[(lane + 64) * HW + base] * inb * ws4[c];
        }
    }
    float ss = v0 * v0 + v1 * v1;
    #pragma unroll
    for (int o = 32; o > 0; o >>= 1) ss += __shfl_xor(ss, o);
    if (ss == 0.0f) ss = 1.0f;   // padding lines: avoid 0/0 NaN
    float nrm = sqrtf(ss);
    float v0n = v0 / nrm, v1n = v1 / nrm;
    Dout[pt * DD + lane] = v0n;
    Dout[pt * DD + 64 + lane] = v1n;
    if (lane == 0) valout[pt] = (line < NLINES) ? validf : 0.0f;

    // bf16 hi/lo split into fragment-major extended operand
    // A role: [hi, lo, hi]; B role: [hi, hi, lo]
    #pragma unroll
    for (int half = 0; half < 2; ++half) {
        float x = half ? v1n : v0n;
        int d = lane + 64 * half;
        __hip_bfloat16 h = __float2bfloat16(x);
        float hf = __bfloat162float(h);
        __hip_bfloat16 l = __float2bfloat16(x - hf);
        short hs = *(short*)&h;
        short lo = *(short*)&l;
        Ef[fragidx(pt, d)] = hs;
        Ef[fragidx(pt, d + 128)] = arole ? lo : hs;
        Ef[fragidx(pt, d + 256)] = arole ? hs : lo;
    }
}

// ---------------- K2: MFMA score GEMM + fused per-line-pair reduction -----
// Block: 160x160 points (32x32 lines), 4 waves 2x2, each wave 80x80 via
// 5x5 tiles of mfma_f32_16x16x32_bf16 over K=384. Fragment-major LDS:
// all ds_read_b128 are base + lane*16 (conflict-free).
__launch_bounds__(256, 3)
__global__ void score_kernel(const short* __restrict__ Af, const short* __restrict__ Bf,
                             const float* __restrict__ val1, const float* __restrict__ val2,
                             float* __restrict__ lsc, float* __restrict__ lscT) {
    __shared__ union {
        struct { short A[20 * 512]; short B[20 * 512]; } st;   // 40960 B
        float dump[80 * 161];                                   // 51520 B
    } u;

    const int t = threadIdx.x;
    const int lane = t & 63;
    const int w = t >> 6;           // wave 0..3
    const int wm = w >> 1;          // 0..1 row half
    const int wn = w & 1;           // 0..1 col half
    const int gA0 = blockIdx.x * 10;   // first 16-pt group of A side
    const int gB0 = blockIdx.y * 10;

    f32x4 acc[5][5];
    #pragma unroll
    for (int a = 0; a < 5; ++a)
        #pragma unroll
        for (int b = 0; b < 5; ++b)
            acc[a][b] = (f32x4){0.f, 0.f, 0.f, 0.f};

    for (int c0 = 0; c0 < NCH; c0 += 2) {
        __syncthreads();
        #pragma unroll
        for (int p = 0; p < 5; ++p) {
            int slot = w * 5 + p;            // 0..19
            int gi = slot >> 1, cc = slot & 1;
            const short* ga = Af + ((size_t)((gA0 + gi) * NCH + c0 + cc) * 64 + lane) * 8;
            async_cp16(ga, &u.st.A[slot * 512]);
            const short* gb = Bf + ((size_t)((gB0 + gi) * NCH + c0 + cc) * 64 + lane) * 8;
            async_cp16(gb, &u.st.B[slot * 512]);
        }
        __syncthreads();
        #pragma unroll
        for (int ks = 0; ks < 2; ++ks) {
            short8 af[5], bf_[5];
            #pragma unroll
            for (int ti = 0; ti < 5; ++ti)
                af[ti] = *(const short8*)&u.st.A[((5 * wm + ti) * 2 + ks) * 512 + lane * 8];
            #pragma unroll
            for (int tj = 0; tj < 5; ++tj)
                bf_[tj] = *(const short8*)&u.st.B[((5 * wn + tj) * 2 + ks) * 512 + lane * 8];
            #pragma unroll
            for (int ti = 0; ti < 5; ++ti)
                #pragma unroll
                for (int tj = 0; tj < 5; ++tj)
                    acc[ti][tj] = __builtin_amdgcn_mfma_f32_16x16x32_bf16(
                        af[ti], bf_[tj], acc[ti][tj], 0, 0, 0);
        }
    }

    // fused epilogue: two phases of 80 rows through LDS, then 5x5 reduction
    const int i0l = blockIdx.x * 32;
    const int j0l = blockIdx.y * 32;
    #pragma unroll
    for (int p = 0; p < 2; ++p) {
        __syncthreads();
        if (wm == p) {
            #pragma unroll
            for (int ti = 0; ti < 5; ++ti) {
                #pragma unroll
                for (int reg = 0; reg < 4; ++reg) {
                    int rloc = 16 * ti + (lane >> 4) * 4 + reg;
                    #pragma unroll
                    for (int tj = 0; tj < 5; ++tj) {
                        int col = 80 * wn + 16 * tj + (lane & 15);
                        u.dump[rloc * 161 + col] = acc[ti][tj][reg];
                    }
                }
            }
        }
        __syncthreads();
        #pragma unroll
        for (int e = 0; e < 2; ++e) {
            int q = t * 2 + e;            // 0..511 line pairs
            int li = q >> 5, lj = q & 31;
            int i = i0l + 16 * p + li;
            int j = j0l + lj;
            if (i < NLINES && j < NLINES) {
                float S[5][5];
                #pragma unroll
                for (int a = 0; a < 5; ++a) {
                    float va = val1[i * NS + a];
                    #pragma unroll
                    for (int b = 0; b < 5; ++b) {
                        float vb = val2[j * NS + b];
                        float sc = u.dump[(li * 5 + a) * 161 + (lj * 5 + b)];
                        S[a][b] = (va != 0.0f && vb != 0.0f) ? sc : -1.0f;
                    }
                }
                float sum1 = 0.0f, cnt1 = 0.0f;
                #pragma unroll
                for (int a = 0; a < 5; ++a) {
                    float r = S[a][0];
                    #pragma unroll
                    for (int b = 1; b < 5; ++b) r = fmaxf(r, S[a][b]);
                    float v = (r != -1.0f) ? 1.0f : 0.0f;
                    sum1 += r * v; cnt1 += v;
                }
                float sum2 = 0.0f, cnt2 = 0.0f;
                #pragma unroll
                for (int b = 0; b < 5; ++b) {
                    float r = S[0][b];
                    #pragma unroll
                    for (int a = 1; a < 5; ++a) r = fmaxf(r, S[a][b]);
                    float v = (r != -1.0f) ? 1.0f : 0.0f;
                    sum2 += r * v; cnt2 += v;
                }
                float res = (sum1 / cnt1 + sum2 / cnt2) * 0.5f;
                lsc[i * NLINES + j] = res;
                lscT[j * NLINES + i] = res;
            }
        }
    }
}

// ------- K3a: per-row top-10, register-resident (stable-argsort ties) -----
__global__ void topk_kernel(const float* __restrict__ ls, int* __restrict__ topk) {
    __shared__ float wv[4];
    __shared__ int wi[4];
    int row = blockIdx.x;
    int t = threadIdx.x;
    int lane = t & 63, w = t >> 6;
    float val[5];
    #pragma unroll
    for (int s = 0; s < 5; ++s) {
        int j = t + 256 * s;
        val[s] = (j < NLINES) ? ls[row * NLINES + j] : -1e30f;
    }
    // local best (tie -> larger j; scan ascending with >=)
    float bv = -1e30f; int bi = -1;
    #pragma unroll
    for (int s = 0; s < 5; ++s) {
        int j = t + 256 * s;
        if (val[s] >= bv) { bv = val[s]; bi = j; }
    }
    for (int sel = 0; sel < 10; ++sel) {
        float rv = bv; int ri = bi;
        #pragma unroll
        for (int o = 32; o > 0; o >>= 1) {
            float ov = __shfl_xor(rv, o);
            int oi = __shfl_xor(ri, o);
            if (ov > rv || (ov == rv && oi > ri)) { rv = ov; ri = oi; }
        }
        if (lane == 0) { wv[w] = rv; wi[w] = ri; }
        __syncthreads();
        float fv = wv[0]; int fi = wi[0];
        #pragma unroll
        for (int qq = 1; qq < 4; ++qq)
            if (wv[qq] > fv || (wv[qq] == fv && wi[qq] > fi)) { fv = wv[qq]; fi = wi[qq]; }
        if (t == 0) topk[row * 10 + 9 - sel] = fi;
        if ((fi & 255) == t) {
            val[fi >> 8] = -1e30f;
            bv = -1e30f; bi = -1;
            #pragma unroll
            for (int s = 0; s < 5; ++s) {
                int j = t + 256 * s;
                if (val[s] >= bv) { bv = val[s]; bi = j; }
            }
        }
        __syncthreads();
    }
}

// ---------------- K3b: Needleman-Wunsch on top-10 (both directions) -------
__device__ __forceinline__ float nw5(const float* M) {
    float F[6] = {0, 0, 0, 0, 0, 0};
    #pragma unroll
    for (int x = 0; x < 5; ++x) {
        float diag = F[0];
        float left = 0.0f;
        #pragma unroll
        for (int y = 1; y <= 5; ++y) {
            float up = F[y];
            float cur = fmaxf(fmaxf(left, up), diag + (M[x * 5 + y - 1] - GAPC));
            F[y] = cur; left = cur; diag = up;
        }
    }
    return F[5];
}

__global__ void nw_kernel(const float* __restrict__ D1, const float* __restrict__ D2,
                          const float* __restrict__ val1, const float* __restrict__ val2,
                          const int* __restrict__ topk1, const int* __restrict__ topk2,
                          float* __restrict__ nwout, float* __restrict__ nw2buf) {
    int w = (blockIdx.x * blockDim.x + threadIdx.x) >> 6;
    int lane = threadIdx.x & 63;
    if (w >= 24000) return;
    int dir = (w >= 12000) ? 1 : 0;
    int rem = w - dir * 12000;
    int row = rem / 10, r = rem - (rem / 10) * 10;
    int i, j;
    if (!dir) { i = row; j = topk1[row * 10 + r]; }
    else      { j = row; i = topk2[row * 10 + r]; }

    float d1a[5], d1b[5], d2a[5], d2b[5];
    #pragma unroll
    for (int p = 0; p < 5; ++p) {
        d1a[p] = D1[(i * NS + p) * DD + lane];
        d1b[p] = D1[(i * NS + p) * DD + 64 + lane];
        d2a[p] = D2[(j * NS + p) * DD + lane];
        d2b[p] = D2[(j * NS + p) * DD + 64 + lane];
    }
    float part[25];
    #pragma unroll
    for (int a = 0; a < 5; ++a)
        #pragma unroll
        for (int b = 0; b < 5; ++b)
            part[a * 5 + b] = d1a[a] * d2a[b] + d1b[a] * d2b[b];
    #pragma unroll
    for (int o = 32; o > 0; o >>= 1) {
        #pragma unroll
        for (int q = 0; q < 25; ++q) part[q] += __shfl_xor(part[q], o);
    }
    if (lane == 0) {
        float S[25];
        #pragma unroll
        for (int a = 0; a < 5; ++a) {
            float va = val1[i * NS + a];
            #pragma unroll
            for (int b = 0; b < 5; ++b) {
                float vb = val2[j * NS + b];
                S[a * 5 + b] = (va != 0.0f && vb != 0.0f) ? part[a * 5 + b] : -1.0f;
            }
        }
        float M1[25], M2[25];
        if (!dir) {
            #pragma unroll
            for (int x = 0; x < 5; ++x)
                #pragma unroll
                for (int y = 0; y < 5; ++y) {
                    M1[x * 5 + y] = S[x * 5 + y];
                    M2[x * 5 + y] = S[x * 5 + (4 - y)];
                }
        } else {
            #pragma unroll
            for (int x = 0; x < 5; ++x)
                #pragma unroll
                for (int y = 0; y < 5; ++y) {
                    M1[x * 5 + y] = S[y * 5 + x];
                    M2[x * 5 + y] = S[(4 - y) * 5 + x];
                }
        }
        float n1 = nw5(M1);
        float n2 = nw5(M2);
        if (!dir) { nwout[row * 20 + r] = n1; nwout[row * 20 + 10 + r] = n2; }
        else      { nw2buf[row * 20 + r] = n1; nw2buf[row * 20 + 10 + r] = n2; }
    }
}

// ---------------- K3c: argmax over 20 + mutual check ----------------------
__global__ void argmax_kernel(const float* __restrict__ nw1, const float* __restrict__ nw2,
                              const int* __restrict__ topk1, const int* __restrict__ topk2,
                              int* __restrict__ mpre, int* __restrict__ m2) {
    int t = blockIdx.x * 256 + threadIdx.x;
    if (t >= 2400) return;
    int dir = t / NLINES, row = t - dir * NLINES;
    const float* nw = (dir ? nw2 : nw1) + row * 20;
    float best = nw[0]; int bi = 0;
    #pragma unroll
    for (int q = 1; q < 20; ++q) {
        float v = nw[q];
        if (v > best) { best = v; bi = q; }
    }
    int m = (dir ? topk2 : topk1)[row * 10 + (bi % 10)];
    if (dir) m2[row] = m; else mpre[row] = m;
}

__global__ void final_kernel(const int* __restrict__ mpre, const int* __restrict__ m2,
                             float* __restrict__ out) {
    int i = blockIdx.x * 256 + threadIdx.x;
    if (i >= NLINES) return;
    int m = mpre[i];
    out[i] = (m2[m] == i) ? (float)m : -1.0f;
}

extern "C" void kernel_launch(void* const* d_in, const int* in_sizes, int n_in,
                              void* d_out, int out_size, void* d_ws, size_t ws_size,
                              hipStream_t stream) {
    const float* lseg1 = (const float*)d_in[0];
    const float* lseg2 = (const float*)d_in[1];
    const float* desc1 = (const float*)d_in[2];
    const float* desc2 = (const float*)d_in[3];
    float* out = (float*)d_out;

    float* wsf = (float*)d_ws;
    size_t off = 0;
    float* D1 = wsf + off;     off += (size_t)PPAD * DD;
    float* D2 = wsf + off;     off += (size_t)PPAD * DD;
    float* val1 = wsf + off;   off += PPAD;
    float* val2 = wsf + off;   off += PPAD;
    float* lsc = wsf + off;    off += (size_t)NLINES * NLINES;
    float* lscT = wsf + off;   off += (size_t)NLINES * NLINES;
    int* topk1 = (int*)(wsf + off); off += NLINES * 10;
    int* topk2 = (int*)(wsf + off); off += NLINES * 10;
    int* mpre = (int*)(wsf + off);  off += 1280;
    int* m2 = (int*)(wsf + off);    off += 1280;
    float* nw2buf = wsf + off; off += NLINES * 20;
    short* Aext = (short*)(wsf + off); off += (size_t)PPAD * KEXT / 2;
    short* Bext = (short*)(wsf + off); off += (size_t)PPAD * KEXT / 2;
    float* tdesc1 = wsf + off; off += (size_t)HW * DD;
    float* tdesc2 = wsf + off; off += (size_t)HW * DD;
    size_t need_full = off * sizeof(float);
    int use_t = (ws_size >= need_full) ? 1 : 0;

    if (use_t) {
        transpose_desc<<<dim3(HW / 32, DD / 32), dim3(32, 8), 0, stream>>>(desc1, tdesc1);
        transpose_desc<<<dim3(HW / 32, DD / 32), dim3(32, 8), 0, stream>>>(desc2, tdesc2);
    }
    sample_kernel<<<PPAD / 4, 256, 0, stream>>>(lseg1, tdesc1, desc1, D1, val1, Aext, 1, use_t);
    sample_kernel<<<PPAD / 4, 256, 0, stream>>>(lseg2, tdesc2, desc2, D2, val2, Bext, 0, use_t);

    score_kernel<<<dim3(NPAD / 32, NPAD / 32), 256, 0, stream>>>(Aext, Bext, val1, val2,
                                                                 lsc, lscT);

    topk_kernel<<<NLINES, 256, 0, stream>>>(lsc, topk1);
    topk_kernel<<<NLINES, 256, 0, stream>>>(lscT, topk2);

    nw_kernel<<<24000 / 4, 256, 0, stream>>>(D1, D2, val1, val2, topk1, topk2,
                                             out + NLINES, nw2buf);

    argmax_kernel<<<10, 256, 0, stream>>>(out + NLINES, nw2buf, topk1, topk2, mpre, m2);
    final_kernel<<<5, 256, 0, stream>>>(mpre, m2, out);
}

// Round 4
// 233.034 us; speedup vs baseline: 1.0535x; 1.0535x over previous
//
#include <hip/hip_runtime.h>
#include <hip/hip_bf16.h>

// SOLD2 line matching on MI355X.
// Inputs: line_seg1 (1200,2,2) f32, line_seg2 (1200,2,2) f32,
//         desc1 (1,128,128,128) f32, desc2 (1,128,128,128) f32
// Outputs (concat float32): matches (1200,), nw (1200,20)

#define NLINES 1200
#define NS 5
#define DD 128
#define HH 128
#define WW 128
#define HW (HH*WW)
#define IMGM1 511.0f
#define GAPC 0.1f
#define NPAD 1216          // 38*32
#define PPAD (NPAD*NS)     // 6080 padded points
#define KEXT 384           // 3-term bf16 split: [hi,lo,hi] x [hi,hi,lo]
#define NCH (KEXT/32)      // 12 k-chunks of 32
#define NGRP (PPAD/16)     // 380 16-pt groups

typedef __attribute__((ext_vector_type(8))) short short8;
typedef __attribute__((ext_vector_type(4))) float f32x4;

__device__ __forceinline__ void async_cp16(const void* g, void* l) {
    __builtin_amdgcn_global_load_lds(
        (const __attribute__((address_space(1))) void*)g,
        (__attribute__((address_space(3))) void*)l, 16, 0, 0);
}

// ---------------- K0: transpose desc [D][H][W] -> [H*W][D] ----------------
__global__ void transpose_desc(const float* __restrict__ in, float* __restrict__ out) {
    __shared__ float t[32][33];
    int s0 = blockIdx.x * 32;          // HW dim
    int d0 = blockIdx.y * 32;          // D dim
    int c = threadIdx.x;               // 0..31
    int r0 = threadIdx.y;              // 0..7
    #pragma unroll
    for (int rr = 0; rr < 32; rr += 8) {
        int d = d0 + r0 + rr;
        t[r0 + rr][c] = in[d * HW + s0 + c];
    }
    __syncthreads();
    #pragma unroll
    for (int rr = 0; rr < 32; rr += 8) {
        int s = s0 + r0 + rr;
        out[s * DD + d0 + c] = t[c][r0 + rr];
    }
}

// ------- K1: sample line points + bilinear descriptors --------------------
__global__ void sample_kernel(const float* __restrict__ lseg,
                              const float* __restrict__ tdesc,  // [HW][D] (if use_t)
                              const float* __restrict__ desc,   // [D][H][W]
                              float* __restrict__ Dout,         // [PPAD][128]
                              float* __restrict__ valout,       // [PPAD]
                              int use_t) {
    int wave = (blockIdx.x * blockDim.x + threadIdx.x) >> 6;
    int lane = threadIdx.x & 63;
    int pt = wave;                      // 0..PPAD-1
    if (pt >= PPAD) return;
    int line = pt / NS;
    int k = pt - line * NS;

    float sy = 0.f, sx = 0.f, ey = 0.f, ex = 0.f;
    if (line < NLINES) {
        sy = lseg[line * 4 + 0]; sx = lseg[line * 4 + 1];
        ey = lseg[line * 4 + 2]; ex = lseg[line * 4 + 3];
    }
    float dy = ey - sy, dx = ex - sx;
    float len = sqrtf(dy * dy + dx * dx);
    float ns = floorf(len * 0.125f);
    ns = fminf(fmaxf(ns, 2.0f), 5.0f);
    float kf = (float)k;
    float validf = (kf < ns) ? 1.0f : 0.0f;
    float py = sy + kf * (dy / (ns - 1.0f));
    float px = sx + kf * (dx / (ns - 1.0f));
    if (validf == 0.0f) { py = 0.0f; px = 0.0f; }

    float xn = 2.0f * px / IMGM1 - 1.0f;
    float yn = 2.0f * py / IMGM1 - 1.0f;
    float ix = ((xn + 1.0f) * (float)WW - 1.0f) * 0.5f;
    float iy = ((yn + 1.0f) * (float)HH - 1.0f) * 0.5f;
    float x0f = floorf(ix), y0f = floorf(iy);
    float wx = ix - x0f, wy = iy - y0f;
    int x0 = (int)x0f, y0 = (int)y0f;

    float w00 = (1.0f - wx) * (1.0f - wy);
    float w10 = wx * (1.0f - wy);
    float w01 = (1.0f - wx) * wy;
    float w11 = wx * wy;

    float v0 = 0.0f, v1 = 0.0f;
    int xs[4] = { x0, x0 + 1, x0,     x0 + 1 };
    int ys[4] = { y0, y0,     y0 + 1, y0 + 1 };
    float ws4[4] = { w00, w10, w01, w11 };
    #pragma unroll
    for (int c = 0; c < 4; ++c) {
        int xi = xs[c], yi = ys[c];
        float inb = (xi >= 0 && xi < WW && yi >= 0 && yi < HH) ? 1.0f : 0.0f;
        int xc = min(max(xi, 0), WW - 1);
        int yc = min(max(yi, 0), HH - 1);
        if (use_t) {
            int base = (yc * WW + xc) * DD;
            v0 += tdesc[base + lane] * inb * ws4[c];
            v1 += tdesc[base + 64 + lane] * inb * ws4[c];
        } else {
            int base = yc * WW + xc;
            v0 += desc[lane * HW + base] * inb * ws4[c];
            v1 += desc[(lane + 64) * HW + base] * inb * ws4[c];
        }
    }
    float ss = v0 * v0 + v1 * v1;
    #pragma unroll
    for (int o = 32; o > 0; o >>= 1) ss += __shfl_xor(ss, o);
    if (ss == 0.0f) ss = 1.0f;   // padding lines: avoid 0/0 NaN
    float nrm = sqrtf(ss);
    Dout[pt * DD + lane] = v0 / nrm;
    Dout[pt * DD + 64 + lane] = v1 / nrm;
    if (lane == 0) valout[pt] = (line < NLINES) ? validf : 0.0f;
}

// ------- K1b: pack fp32 desc -> fragment-major 3-term bf16 operand --------
// Ef block (g, c) is 1024B: lane l = q*16+r holds shorts for
// pt = g*16+r, kext = c*32 + q*8 + (0..7). Fully coalesced 16B/thread writes.
// A role: [hi, lo, hi]; B role: [hi, hi, lo]
__global__ void pack_kernel(const float* __restrict__ D, short* __restrict__ Ef, int arole) {
    __shared__ float ds[16][129];
    int g = blockIdx.x;                // 16-pt group
    int t = threadIdx.x;               // 0..255
    #pragma unroll
    for (int s = 0; s < 8; ++s) {
        int idx = s * 256 + t;         // 0..2047
        int r = idx >> 7, k = idx & 127;
        ds[r][k] = D[((size_t)g * 16 + r) * DD + k];
    }
    __syncthreads();
    #pragma unroll
    for (int it = 0; it < 3; ++it) {
        int idx = it * 256 + t;        // 0..767 = 12 chunks x 64 lanes
        int c = idx >> 6, l = idx & 63;
        int q = l >> 4, r = l & 15;
        short8 outv;
        #pragma unroll
        for (int jj = 0; jj < 8; ++jj) {
            int kext = c * 32 + q * 8 + jj;
            int term = kext >> 7, k = kext & 127;
            float x = ds[r][k];
            __hip_bfloat16 h = __float2bfloat16(x);
            short v = *(short*)&h;
            bool lo_term = arole ? (term == 1) : (term == 2);
            if (lo_term) {
                float hf = __bfloat162float(h);
                __hip_bfloat16 lw = __float2bfloat16(x - hf);
                v = *(short*)&lw;
            }
            outv[jj] = v;
        }
        *(short8*)&Ef[((size_t)(g * NCH + c) * 64 + l) * 8] = outv;
    }
}

// ---------------- K2: MFMA score GEMM + fused per-line-pair reduction -----
// Block: 160x160 points (32x32 lines), 4 waves 2x2, each wave 80x80 via
// 5x5 tiles of mfma_f32_16x16x32_bf16 over KEXT=384 in 12 chunks of 32.
// Double-buffered LDS staging: loads for chunk c+1 drain during compute(c).
__launch_bounds__(256, 2)
__global__ void score_kernel(const short* __restrict__ Af, const short* __restrict__ Bf,
                             const float* __restrict__ val1, const float* __restrict__ val2,
                             float* __restrict__ lsc) {
    __shared__ union {
        struct { short A[2][5120]; short B[2][5120]; } st;   // 40960 B
        float dump[80 * 161];                                 // 51520 B
    } u;

    const int t = threadIdx.x;
    const int lane = t & 63;
    const int w = t >> 6;           // wave 0..3
    const int wm = w >> 1;          // 0..1 row half
    const int wn = w & 1;           // 0..1 col half
    const int gA0 = blockIdx.x * 10;   // first 16-pt group of A side
    const int gB0 = blockIdx.y * 10;

    f32x4 acc[5][5];
    #pragma unroll
    for (int a = 0; a < 5; ++a)
        #pragma unroll
        for (int b = 0; b < 5; ++b)
            acc[a][b] = (f32x4){0.f, 0.f, 0.f, 0.f};

    // stage chunk c into buffer b: 20 slots (10 A + 10 B), 5 per wave
    auto issue = [&](int c, int b) {
        #pragma unroll
        for (int p = 0; p < 5; ++p) {
            int idx = w * 5 + p;          // 0..19, side is wave-uniform
            if (idx < 10) {
                const short* g = Af + ((size_t)((gA0 + idx) * NCH + c) * 64 + lane) * 8;
                async_cp16(g, &u.st.A[b][idx * 512]);
            } else {
                int gi = idx - 10;
                const short* g = Bf + ((size_t)((gB0 + gi) * NCH + c) * 64 + lane) * 8;
                async_cp16(g, &u.st.B[b][gi * 512]);
            }
        }
    };

    issue(0, 0);
    for (int c = 0; c < NCH; ++c) {
        __syncthreads();                        // drains loads(c) (in flight 1 iter)
        if (c + 1 < NCH) issue(c + 1, (c + 1) & 1);
        int b = c & 1;
        short8 af[5], bf_[5];
        #pragma unroll
        for (int ti = 0; ti < 5; ++ti)
            af[ti] = *(const short8*)&u.st.A[b][(5 * wm + ti) * 512 + lane * 8];
        #pragma unroll
        for (int tj = 0; tj < 5; ++tj)
            bf_[tj] = *(const short8*)&u.st.B[b][(5 * wn + tj) * 512 + lane * 8];
        #pragma unroll
        for (int ti = 0; ti < 5; ++ti)
            #pragma unroll
            for (int tj = 0; tj < 5; ++tj)
                acc[ti][tj] = __builtin_amdgcn_mfma_f32_16x16x32_bf16(
                    af[ti], bf_[tj], acc[ti][tj], 0, 0, 0);
    }

    // fused epilogue: two phases of 80 rows through LDS, then 5x5 reduction
    const int i0l = blockIdx.x * 32;
    const int j0l = blockIdx.y * 32;
    #pragma unroll
    for (int p = 0; p < 2; ++p) {
        __syncthreads();
        if (wm == p) {
            #pragma unroll
            for (int ti = 0; ti < 5; ++ti) {
                #pragma unroll
                for (int reg = 0; reg < 4; ++reg) {
                    int rloc = 16 * ti + (lane >> 4) * 4 + reg;
                    #pragma unroll
                    for (int tj = 0; tj < 5; ++tj) {
                        int col = 80 * wn + 16 * tj + (lane & 15);
                        u.dump[rloc * 161 + col] = acc[ti][tj][reg];
                    }
                }
            }
        }
        __syncthreads();
        #pragma unroll
        for (int e = 0; e < 2; ++e) {
            int q = t * 2 + e;            // 0..511 line pairs
            int li = q >> 5, lj = q & 31;
            int i = i0l + 16 * p + li;
            int j = j0l + lj;
            if (i < NLINES && j < NLINES) {
                float S[5][5];
                #pragma unroll
                for (int a = 0; a < 5; ++a) {
                    float va = val1[i * NS + a];
                    #pragma unroll
                    for (int b = 0; b < 5; ++b) {
                        float vb = val2[j * NS + b];
                        float sc = u.dump[(li * 5 + a) * 161 + (lj * 5 + b)];
                        S[a][b] = (va != 0.0f && vb != 0.0f) ? sc : -1.0f;
                    }
                }
                float sum1 = 0.0f, cnt1 = 0.0f;
                #pragma unroll
                for (int a = 0; a < 5; ++a) {
                    float r = S[a][0];
                    #pragma unroll
                    for (int b = 1; b < 5; ++b) r = fmaxf(r, S[a][b]);
                    float v = (r != -1.0f) ? 1.0f : 0.0f;
                    sum1 += r * v; cnt1 += v;
                }
                float sum2 = 0.0f, cnt2 = 0.0f;
                #pragma unroll
                for (int b = 0; b < 5; ++b) {
                    float r = S[0][b];
                    #pragma unroll
                    for (int a = 1; a < 5; ++a) r = fmaxf(r, S[a][b]);
                    float v = (r != -1.0f) ? 1.0f : 0.0f;
                    sum2 += r * v; cnt2 += v;
                }
                lsc[i * NLINES + j] = (sum1 / cnt1 + sum2 / cnt2) * 0.5f;
            }
        }
    }
}

// ---------------- K2b: transpose lsc (full-line reads/writes) -------------
__global__ void transpose_lsc(const float* __restrict__ in, float* __restrict__ out) {
    __shared__ float t[32][33];
    int x0 = blockIdx.x * 32, y0 = blockIdx.y * 32;
    int c = threadIdx.x, r0 = threadIdx.y;      // 32 x 8
    #pragma unroll
    for (int rr = 0; rr < 32; rr += 8) {
        int y = y0 + r0 + rr, x = x0 + c;
        if (y < NLINES && x < NLINES) t[r0 + rr][c] = in[y * NLINES + x];
    }
    __syncthreads();
    #pragma unroll
    for (int rr = 0; rr < 32; rr += 8) {
        int x = x0 + r0 + rr, y = y0 + c;
        if (x < NLINES && y < NLINES) out[x * NLINES + y] = t[c][r0 + rr];
    }
}

// ------- K3a: per-row top-10, register-resident (stable-argsort ties) -----
__global__ void topk_kernel(const float* __restrict__ ls, int* __restrict__ topk) {
    __shared__ float wv[4];
    __shared__ int wi[4];
    int row = blockIdx.x;
    int t = threadIdx.x;
    int lane = t & 63, w = t >> 6;
    float val[5];
    #pragma unroll
    for (int s = 0; s < 5; ++s) {
        int j = t + 256 * s;
        val[s] = (j < NLINES) ? ls[row * NLINES + j] : -1e30f;
    }
    float bv = -1e30f; int bi = -1;
    #pragma unroll
    for (int s = 0; s < 5; ++s) {
        int j = t + 256 * s;
        if (val[s] >= bv) { bv = val[s]; bi = j; }
    }
    for (int sel = 0; sel < 10; ++sel) {
        float rv = bv; int ri = bi;
        #pragma unroll
        for (int o = 32; o > 0; o >>= 1) {
            float ov = __shfl_xor(rv, o);
            int oi = __shfl_xor(ri, o);
            if (ov > rv || (ov == rv && oi > ri)) { rv = ov; ri = oi; }
        }
        if (lane == 0) { wv[w] = rv; wi[w] = ri; }
        __syncthreads();
        float fv = wv[0]; int fi = wi[0];
        #pragma unroll
        for (int qq = 1; qq < 4; ++qq)
            if (wv[qq] > fv || (wv[qq] == fv && wi[qq] > fi)) { fv = wv[qq]; fi = wi[qq]; }
        if (t == 0) topk[row * 10 + 9 - sel] = fi;
        if ((fi & 255) == t) {
            val[fi >> 8] = -1e30f;
            bv = -1e30f; bi = -1;
            #pragma unroll
            for (int s = 0; s < 5; ++s) {
                int j = t + 256 * s;
                if (val[s] >= bv) { bv = val[s]; bi = j; }
            }
        }
        __syncthreads();
    }
}

// ---------------- K3b: Needleman-Wunsch on top-10 (both directions) -------
__device__ __forceinline__ float nw5(const float* M) {
    float F[6] = {0, 0, 0, 0, 0, 0};
    #pragma unroll
    for (int x = 0; x < 5; ++x) {
        float diag = F[0];
        float left = 0.0f;
        #pragma unroll
        for (int y = 1; y <= 5; ++y) {
            float up = F[y];
            float cur = fmaxf(fmaxf(left, up), diag + (M[x * 5 + y - 1] - GAPC));
            F[y] = cur; left = cur; diag = up;
        }
    }
    return F[5];
}

__global__ void nw_kernel(const float* __restrict__ D1, const float* __restrict__ D2,
                          const float* __restrict__ val1, const float* __restrict__ val2,
                          const int* __restrict__ topk1, const int* __restrict__ topk2,
                          float* __restrict__ nwout, float* __restrict__ nw2buf) {
    int w = (blockIdx.x * blockDim.x + threadIdx.x) >> 6;
    int lane = threadIdx.x & 63;
    if (w >= 24000) return;
    int dir = (w >= 12000) ? 1 : 0;
    int rem = w - dir * 12000;
    int row = rem / 10, r = rem - (rem / 10) * 10;
    int i, j;
    if (!dir) { i = row; j = topk1[row * 10 + r]; }
    else      { j = row; i = topk2[row * 10 + r]; }

    float d1a[5], d1b[5], d2a[5], d2b[5];
    #pragma unroll
    for (int p = 0; p < 5; ++p) {
        d1a[p] = D1[(i * NS + p) * DD + lane];
        d1b[p] = D1[(i * NS + p) * DD + 64 + lane];
        d2a[p] = D2[(j * NS + p) * DD + lane];
        d2b[p] = D2[(j * NS + p) * DD + 64 + lane];
    }
    float part[25];
    #pragma unroll
    for (int a = 0; a < 5; ++a)
        #pragma unroll
        for (int b = 0; b < 5; ++b)
            part[a * 5 + b] = d1a[a] * d2a[b] + d1b[a] * d2b[b];
    #pragma unroll
    for (int o = 32; o > 0; o >>= 1) {
        #pragma unroll
        for (int q = 0; q < 25; ++q) part[q] += __shfl_xor(part[q], o);
    }
    if (lane == 0) {
        float S[25];
        #pragma unroll
        for (int a = 0; a < 5; ++a) {
            float va = val1[i * NS + a];
            #pragma unroll
            for (int b = 0; b < 5; ++b) {
                float vb = val2[j * NS + b];
                S[a * 5 + b] = (va != 0.0f && vb != 0.0f) ? part[a * 5 + b] : -1.0f;
            }
        }
        float M1[25], M2[25];
        if (!dir) {
            #pragma unroll
            for (int x = 0; x < 5; ++x)
                #pragma unroll
                for (int y = 0; y < 5; ++y) {
                    M1[x * 5 + y] = S[x * 5 + y];
                    M2[x * 5 + y] = S[x * 5 + (4 - y)];
                }
        } else {
            #pragma unroll
            for (int x = 0; x < 5; ++x)
                #pragma unroll
                for (int y = 0; y < 5; ++y) {
                    M1[x * 5 + y] = S[y * 5 + x];
                    M2[x * 5 + y] = S[(4 - y) * 5 + x];
                }
        }
        float n1 = nw5(M1);
        float n2 = nw5(M2);
        if (!dir) { nwout[row * 20 + r] = n1; nwout[row * 20 + 10 + r] = n2; }
        else      { nw2buf[row * 20 + r] = n1; nw2buf[row * 20 + 10 + r] = n2; }
    }
}

// ---------------- K3c: argmax over 20 + mutual check ----------------------
__global__ void argmax_kernel(const float* __restrict__ nw1, const float* __restrict__ nw2,
                              const int* __restrict__ topk1, const int* __restrict__ topk2,
                              int* __restrict__ mpre, int* __restrict__ m2) {
    int t = blockIdx.x * 256 + threadIdx.x;
    if (t >= 2400) return;
    int dir = t / NLINES, row = t - dir * NLINES;
    const float* nw = (dir ? nw2 : nw1) + row * 20;
    float best = nw[0]; int bi = 0;
    #pragma unroll
    for (int q = 1; q < 20; ++q) {
        float v = nw[q];
        if (v > best) { best = v; bi = q; }
    }
    int m = (dir ? topk2 : topk1)[row * 10 + (bi % 10)];
    if (dir) m2[row] = m; else mpre[row] = m;
}

__global__ void final_kernel(const int* __restrict__ mpre, const int* __restrict__ m2,
                             float* __restrict__ out) {
    int i = blockIdx.x * 256 + threadIdx.x;
    if (i >= NLINES) return;
    int m = mpre[i];
    out[i] = (m2[m] == i) ? (float)m : -1.0f;
}

extern "C" void kernel_launch(void* const* d_in, const int* in_sizes, int n_in,
                              void* d_out, int out_size, void* d_ws, size_t ws_size,
                              hipStream_t stream) {
    const float* lseg1 = (const float*)d_in[0];
    const float* lseg2 = (const float*)d_in[1];
    const float* desc1 = (const float*)d_in[2];
    const float* desc2 = (const float*)d_in[3];
    float* out = (float*)d_out;

    float* wsf = (float*)d_ws;
    size_t off = 0;
    float* D1 = wsf + off;     off += (size_t)PPAD * DD;
    float* D2 = wsf + off;     off += (size_t)PPAD * DD;
    float* val1 = wsf + off;   off += PPAD;
    float* val2 = wsf + off;   off += PPAD;
    float* lsc = wsf + off;    off += (size_t)NLINES * NLINES;
    float* lscT = wsf + off;   off += (size_t)NLINES * NLINES;
    int* topk1 = (int*)(wsf + off); off += NLINES * 10;
    int* topk2 = (int*)(wsf + off); off += NLINES * 10;
    int* mpre = (int*)(wsf + off);  off += 1280;
    int* m2 = (int*)(wsf + off);    off += 1280;
    float* nw2buf = wsf + off; off += NLINES * 20;
    short* Aext = (short*)(wsf + off); off += (size_t)PPAD * KEXT / 2;
    short* Bext = (short*)(wsf + off); off += (size_t)PPAD * KEXT / 2;
    float* tdesc1 = wsf + off; off += (size_t)HW * DD;
    float* tdesc2 = wsf + off; off += (size_t)HW * DD;
    size_t need_full = off * sizeof(float);
    int use_t = (ws_size >= need_full) ? 1 : 0;

    if (use_t) {
        transpose_desc<<<dim3(HW / 32, DD / 32), dim3(32, 8), 0, stream>>>(desc1, tdesc1);
        transpose_desc<<<dim3(HW / 32, DD / 32), dim3(32, 8), 0, stream>>>(desc2, tdesc2);
    }
    sample_kernel<<<PPAD / 4, 256, 0, stream>>>(lseg1, tdesc1, desc1, D1, val1, use_t);
    sample_kernel<<<PPAD / 4, 256, 0, stream>>>(lseg2, tdesc2, desc2, D2, val2, use_t);

    pack_kernel<<<NGRP, 256, 0, stream>>>(D1, Aext, 1);
    pack_kernel<<<NGRP, 256, 0, stream>>>(D2, Bext, 0);

    score_kernel<<<dim3(NPAD / 32, NPAD / 32), 256, 0, stream>>>(Aext, Bext, val1, val2, lsc);

    transpose_lsc<<<dim3(38, 38), dim3(32, 8), 0, stream>>>(lsc, lscT);

    topk_kernel<<<NLINES, 256, 0, stream>>>(lsc, topk1);
    topk_kernel<<<NLINES, 256, 0, stream>>>(lscT, topk2);

    nw_kernel<<<24000 / 4, 256, 0, stream>>>(D1, D2, val1, val2, topk1, topk2,
                                             out + NLINES, nw2buf);

    argmax_kernel<<<10, 256, 0, stream>>>(out + NLINES, nw2buf, topk1, topk2, mpre, m2);
    final_kernel<<<5, 256, 0, stream>>>(mpre, m2, out);
}

// Round 5
// 208.740 us; speedup vs baseline: 1.1761x; 1.1164x over previous
//
#include <hip/hip_runtime.h>
#include <hip/hip_bf16.h>

// SOLD2 line matching on MI355X.
// Inputs: line_seg1 (1200,2,2) f32, line_seg2 (1200,2,2) f32,
//         desc1 (1,128,128,128) f32, desc2 (1,128,128,128) f32
// Outputs (concat float32): matches (1200,), nw (1200,20)

#define NLINES 1200
#define NS 5
#define DD 128
#define HH 128
#define WW 128
#define HW (HH*WW)
#define IMGM1 511.0f
#define GAPC 0.1f
#define NPAD 1216          // 38*32
#define PPAD (NPAD*NS)     // 6080 padded points
#define KEXT 384           // 3-term bf16 split: [hi,lo,hi] x [hi,hi,lo]
#define NCH (KEXT/32)      // 12 k-chunks of 32
#define NGRP (PPAD/16)     // 380 16-pt groups

typedef __attribute__((ext_vector_type(8))) short short8;
typedef __attribute__((ext_vector_type(4))) float f32x4;

// ---------------- K0: transpose desc [D][H][W] -> [H*W][D] ----------------
__global__ void transpose_desc(const float* __restrict__ in, float* __restrict__ out) {
    __shared__ float t[32][33];
    int s0 = blockIdx.x * 32;          // HW dim
    int d0 = blockIdx.y * 32;          // D dim
    int c = threadIdx.x;               // 0..31
    int r0 = threadIdx.y;              // 0..7
    #pragma unroll
    for (int rr = 0; rr < 32; rr += 8) {
        int d = d0 + r0 + rr;
        t[r0 + rr][c] = in[d * HW + s0 + c];
    }
    __syncthreads();
    #pragma unroll
    for (int rr = 0; rr < 32; rr += 8) {
        int s = s0 + r0 + rr;
        out[s * DD + d0 + c] = t[c][r0 + rr];
    }
}

// ------- K1: sample line points + bilinear descriptors --------------------
__global__ void sample_kernel(const float* __restrict__ lseg,
                              const float* __restrict__ tdesc,  // [HW][D] (if use_t)
                              const float* __restrict__ desc,   // [D][H][W]
                              float* __restrict__ Dout,         // [PPAD][128]
                              float* __restrict__ valout,       // [PPAD]
                              int use_t) {
    int wave = (blockIdx.x * blockDim.x + threadIdx.x) >> 6;
    int lane = threadIdx.x & 63;
    int pt = wave;                      // 0..PPAD-1
    if (pt >= PPAD) return;
    int line = pt / NS;
    int k = pt - line * NS;

    float sy = 0.f, sx = 0.f, ey = 0.f, ex = 0.f;
    if (line < NLINES) {
        sy = lseg[line * 4 + 0]; sx = lseg[line * 4 + 1];
        ey = lseg[line * 4 + 2]; ex = lseg[line * 4 + 3];
    }
    float dy = ey - sy, dx = ex - sx;
    float len = sqrtf(dy * dy + dx * dx);
    float ns = floorf(len * 0.125f);
    ns = fminf(fmaxf(ns, 2.0f), 5.0f);
    float kf = (float)k;
    float validf = (kf < ns) ? 1.0f : 0.0f;
    float py = sy + kf * (dy / (ns - 1.0f));
    float px = sx + kf * (dx / (ns - 1.0f));
    if (validf == 0.0f) { py = 0.0f; px = 0.0f; }

    float xn = 2.0f * px / IMGM1 - 1.0f;
    float yn = 2.0f * py / IMGM1 - 1.0f;
    float ix = ((xn + 1.0f) * (float)WW - 1.0f) * 0.5f;
    float iy = ((yn + 1.0f) * (float)HH - 1.0f) * 0.5f;
    float x0f = floorf(ix), y0f = floorf(iy);
    float wx = ix - x0f, wy = iy - y0f;
    int x0 = (int)x0f, y0 = (int)y0f;

    float w00 = (1.0f - wx) * (1.0f - wy);
    float w10 = wx * (1.0f - wy);
    float w01 = (1.0f - wx) * wy;
    float w11 = wx * wy;

    float v0 = 0.0f, v1 = 0.0f;
    int xs[4] = { x0, x0 + 1, x0,     x0 + 1 };
    int ys[4] = { y0, y0,     y0 + 1, y0 + 1 };
    float ws4[4] = { w00, w10, w01, w11 };
    #pragma unroll
    for (int c = 0; c < 4; ++c) {
        int xi = xs[c], yi = ys[c];
        float inb = (xi >= 0 && xi < WW && yi >= 0 && yi < HH) ? 1.0f : 0.0f;
        int xc = min(max(xi, 0), WW - 1);
        int yc = min(max(yi, 0), HH - 1);
        if (use_t) {
            int base = (yc * WW + xc) * DD;
            v0 += tdesc[base + lane] * inb * ws4[c];
            v1 += tdesc[base + 64 + lane] * inb * ws4[c];
        } else {
            int base = yc * WW + xc;
            v0 += desc[lane * HW + base] * inb * ws4[c];
            v1 += desc[(lane + 64) * HW + base] * inb * ws4[c];
        }
    }
    float ss = v0 * v0 + v1 * v1;
    #pragma unroll
    for (int o = 32; o > 0; o >>= 1) ss += __shfl_xor(ss, o);
    if (ss == 0.0f) ss = 1.0f;   // padding lines: avoid 0/0 NaN
    float nrm = sqrtf(ss);
    Dout[pt * DD + lane] = v0 / nrm;
    Dout[pt * DD + 64 + lane] = v1 / nrm;
    if (lane == 0) valout[pt] = (line < NLINES) ? validf : 0.0f;
}

// ------- K1b: pack fp32 desc -> fragment-major 3-term bf16 operand --------
// Ef block (g, c) is 1024B: lane l = q*16+r holds shorts for
// pt = g*16+r, kext = c*32 + q*8 + (0..7). Fully coalesced 16B/thread writes.
// A role: [hi, lo, hi]; B role: [hi, hi, lo]
__global__ void pack_kernel(const float* __restrict__ D, short* __restrict__ Ef, int arole) {
    __shared__ float ds[16][129];
    int g = blockIdx.x;                // 16-pt group
    int t = threadIdx.x;               // 0..255
    #pragma unroll
    for (int s = 0; s < 8; ++s) {
        int idx = s * 256 + t;         // 0..2047
        int r = idx >> 7, k = idx & 127;
        ds[r][k] = D[((size_t)g * 16 + r) * DD + k];
    }
    __syncthreads();
    #pragma unroll
    for (int it = 0; it < 3; ++it) {
        int idx = it * 256 + t;        // 0..767 = 12 chunks x 64 lanes
        int c = idx >> 6, l = idx & 63;
        int q = l >> 4, r = l & 15;
        short8 outv;
        #pragma unroll
        for (int jj = 0; jj < 8; ++jj) {
            int kext = c * 32 + q * 8 + jj;
            int term = kext >> 7, k = kext & 127;
            float x = ds[r][k];
            __hip_bfloat16 h = __float2bfloat16(x);
            short v = *(short*)&h;
            bool lo_term = arole ? (term == 1) : (term == 2);
            if (lo_term) {
                float hf = __bfloat162float(h);
                __hip_bfloat16 lw = __float2bfloat16(x - hf);
                v = *(short*)&lw;
            }
            outv[jj] = v;
        }
        *(short8*)&Ef[((size_t)(g * NCH + c) * 64 + l) * 8] = outv;
    }
}

// ---------------- K2: MFMA score GEMM + fused per-line-pair reduction -----
// Block: 160x160 points (32x32 lines), 4 waves 2x2, each wave 80x80 via
// 5x5 tiles of mfma_f32_16x16x32_bf16 over KEXT=384 in 12 chunks of 32.
// NO LDS in the K-loop: fragment-major layout makes each wave fragment a
// lane-perfect contiguous 1KB global block -> direct global->VGPR loads,
// software double-buffered, no barriers (compiler emits fine vmcnt).
__launch_bounds__(256, 2)
__global__ void score_kernel(const short* __restrict__ Af, const short* __restrict__ Bf,
                             const float* __restrict__ val1, const float* __restrict__ val2,
                             float* __restrict__ lsc) {
    __shared__ float dump[80 * 161];   // epilogue only (51520 B)

    const int t = threadIdx.x;
    const int lane = t & 63;
    const int w = t >> 6;           // wave 0..3
    const int wm = w >> 1;          // 0..1 row half
    const int wn = w & 1;           // 0..1 col half
    const int gA0 = blockIdx.x * 10;   // first 16-pt group of A side
    const int gB0 = blockIdx.y * 10;

    const short* pa[5];
    const short* pb[5];
    #pragma unroll
    for (int ti = 0; ti < 5; ++ti) {
        pa[ti] = Af + ((size_t)(gA0 + 5 * wm + ti) * NCH * 64 + lane) * 8;
        pb[ti] = Bf + ((size_t)(gB0 + 5 * wn + ti) * NCH * 64 + lane) * 8;
    }
    // chunk stride = 64 lanes * 8 shorts = 512 shorts

    f32x4 acc[5][5];
    #pragma unroll
    for (int a = 0; a < 5; ++a)
        #pragma unroll
        for (int b = 0; b < 5; ++b)
            acc[a][b] = (f32x4){0.f, 0.f, 0.f, 0.f};

    short8 ca[5], cb[5], na[5], nb[5];
    #pragma unroll
    for (int ti = 0; ti < 5; ++ti) {
        ca[ti] = *(const short8*)(pa[ti]);
        cb[ti] = *(const short8*)(pb[ti]);
    }
    #pragma unroll
    for (int c = 0; c < NCH; c += 2) {
        // prefetch chunk c+1 while computing c
        #pragma unroll
        for (int ti = 0; ti < 5; ++ti) {
            na[ti] = *(const short8*)(pa[ti] + (c + 1) * 512);
            nb[ti] = *(const short8*)(pb[ti] + (c + 1) * 512);
        }
        #pragma unroll
        for (int ti = 0; ti < 5; ++ti)
            #pragma unroll
            for (int tj = 0; tj < 5; ++tj)
                acc[ti][tj] = __builtin_amdgcn_mfma_f32_16x16x32_bf16(
                    ca[ti], cb[tj], acc[ti][tj], 0, 0, 0);
        if (c + 2 < NCH) {
            #pragma unroll
            for (int ti = 0; ti < 5; ++ti) {
                ca[ti] = *(const short8*)(pa[ti] + (c + 2) * 512);
                cb[ti] = *(const short8*)(pb[ti] + (c + 2) * 512);
            }
        }
        #pragma unroll
        for (int ti = 0; ti < 5; ++ti)
            #pragma unroll
            for (int tj = 0; tj < 5; ++tj)
                acc[ti][tj] = __builtin_amdgcn_mfma_f32_16x16x32_bf16(
                    na[ti], nb[tj], acc[ti][tj], 0, 0, 0);
    }

    // fused epilogue: two phases of 80 rows through LDS, then 5x5 reduction
    const int i0l = blockIdx.x * 32;
    const int j0l = blockIdx.y * 32;
    #pragma unroll
    for (int p = 0; p < 2; ++p) {
        __syncthreads();
        if (wm == p) {
            #pragma unroll
            for (int ti = 0; ti < 5; ++ti) {
                #pragma unroll
                for (int reg = 0; reg < 4; ++reg) {
                    int rloc = 16 * ti + (lane >> 4) * 4 + reg;
                    #pragma unroll
                    for (int tj = 0; tj < 5; ++tj) {
                        int col = 80 * wn + 16 * tj + (lane & 15);
                        dump[rloc * 161 + col] = acc[ti][tj][reg];
                    }
                }
            }
        }
        __syncthreads();
        #pragma unroll
        for (int e = 0; e < 2; ++e) {
            int q = t * 2 + e;            // 0..511 line pairs
            int li = q >> 5, lj = q & 31;
            int i = i0l + 16 * p + li;
            int j = j0l + lj;
            if (i < NLINES && j < NLINES) {
                float S[5][5];
                #pragma unroll
                for (int a = 0; a < 5; ++a) {
                    float va = val1[i * NS + a];
                    #pragma unroll
                    for (int b = 0; b < 5; ++b) {
                        float vb = val2[j * NS + b];
                        float sc = dump[(li * 5 + a) * 161 + (lj * 5 + b)];
                        S[a][b] = (va != 0.0f && vb != 0.0f) ? sc : -1.0f;
                    }
                }
                float sum1 = 0.0f, cnt1 = 0.0f;
                #pragma unroll
                for (int a = 0; a < 5; ++a) {
                    float r = S[a][0];
                    #pragma unroll
                    for (int b = 1; b < 5; ++b) r = fmaxf(r, S[a][b]);
                    float v = (r != -1.0f) ? 1.0f : 0.0f;
                    sum1 += r * v; cnt1 += v;
                }
                float sum2 = 0.0f, cnt2 = 0.0f;
                #pragma unroll
                for (int b = 0; b < 5; ++b) {
                    float r = S[0][b];
                    #pragma unroll
                    for (int a = 1; a < 5; ++a) r = fmaxf(r, S[a][b]);
                    float v = (r != -1.0f) ? 1.0f : 0.0f;
                    sum2 += r * v; cnt2 += v;
                }
                lsc[i * NLINES + j] = (sum1 / cnt1 + sum2 / cnt2) * 0.5f;
            }
        }
    }
}

// ---------------- K2b: transpose lsc (full-line reads/writes) -------------
__global__ void transpose_lsc(const float* __restrict__ in, float* __restrict__ out) {
    __shared__ float t[32][33];
    int x0 = blockIdx.x * 32, y0 = blockIdx.y * 32;
    int c = threadIdx.x, r0 = threadIdx.y;      // 32 x 8
    #pragma unroll
    for (int rr = 0; rr < 32; rr += 8) {
        int y = y0 + r0 + rr, x = x0 + c;
        if (y < NLINES && x < NLINES) t[r0 + rr][c] = in[y * NLINES + x];
    }
    __syncthreads();
    #pragma unroll
    for (int rr = 0; rr < 32; rr += 8) {
        int x = x0 + r0 + rr, y = y0 + c;
        if (x < NLINES && y < NLINES) out[x * NLINES + y] = t[c][r0 + rr];
    }
}

// ------- K3a: per-row top-10, register-resident (stable-argsort ties) -----
__global__ void topk_kernel(const float* __restrict__ ls, int* __restrict__ topk) {
    __shared__ float wv[4];
    __shared__ int wi[4];
    int row = blockIdx.x;
    int t = threadIdx.x;
    int lane = t & 63, w = t >> 6;
    float val[5];
    #pragma unroll
    for (int s = 0; s < 5; ++s) {
        int j = t + 256 * s;
        val[s] = (j < NLINES) ? ls[row * NLINES + j] : -1e30f;
    }
    float bv = -1e30f; int bi = -1;
    #pragma unroll
    for (int s = 0; s < 5; ++s) {
        int j = t + 256 * s;
        if (val[s] >= bv) { bv = val[s]; bi = j; }
    }
    for (int sel = 0; sel < 10; ++sel) {
        float rv = bv; int ri = bi;
        #pragma unroll
        for (int o = 32; o > 0; o >>= 1) {
            float ov = __shfl_xor(rv, o);
            int oi = __shfl_xor(ri, o);
            if (ov > rv || (ov == rv && oi > ri)) { rv = ov; ri = oi; }
        }
        if (lane == 0) { wv[w] = rv; wi[w] = ri; }
        __syncthreads();
        float fv = wv[0]; int fi = wi[0];
        #pragma unroll
        for (int qq = 1; qq < 4; ++qq)
            if (wv[qq] > fv || (wv[qq] == fv && wi[qq] > fi)) { fv = wv[qq]; fi = wi[qq]; }
        if (t == 0) topk[row * 10 + 9 - sel] = fi;
        if ((fi & 255) == t) {
            val[fi >> 8] = -1e30f;
            bv = -1e30f; bi = -1;
            #pragma unroll
            for (int s = 0; s < 5; ++s) {
                int j = t + 256 * s;
                if (val[s] >= bv) { bv = val[s]; bi = j; }
            }
        }
        __syncthreads();
    }
}

// ---------------- K3b: Needleman-Wunsch via one masked MFMA per pair ------
__device__ __forceinline__ float nw5(const float* M) {
    float F[6] = {0, 0, 0, 0, 0, 0};
    #pragma unroll
    for (int x = 0; x < 5; ++x) {
        float diag = F[0];
        float left = 0.0f;
        #pragma unroll
        for (int y = 1; y <= 5; ++y) {
            float up = F[y];
            float cur = fmaxf(fmaxf(left, up), diag + (M[x * 5 + y - 1] - GAPC));
            F[y] = cur; left = cur; diag = up;
        }
    }
    return F[5];
}

__global__ void nw_kernel(const short* __restrict__ Af, const short* __restrict__ Bf,
                          const float* __restrict__ val1, const float* __restrict__ val2,
                          const int* __restrict__ topk1, const int* __restrict__ topk2,
                          float* __restrict__ nwout, float* __restrict__ nw2buf) {
    __shared__ float sbuf[4][25];
    int w4 = threadIdx.x >> 6;              // wave in block
    int gw = blockIdx.x * 4 + w4;           // 0..23999
    int lane = threadIdx.x & 63;
    int dir = (gw >= 12000) ? 1 : 0;
    int rem = gw - dir * 12000;
    int row = rem / 10, r = rem - row * 10;
    int i, j;
    if (!dir) { i = row; j = topk1[row * 10 + r]; }
    else      { j = row; i = topk2[row * 10 + r]; }

    // masked MFMA: rows m=0..4 are pts i*5.., cols n=0..4 are pts j*5..
    // (m,n >= 5 lanes load valid-but-unused neighbor points)
    int q = lane >> 4, rr = lane & 15;
    int ptA = i * 5 + rr, ptB = j * 5 + rr;
    const short* baseA = Af + ((size_t)((ptA >> 4) * NCH) * 64 + q * 16 + (ptA & 15)) * 8;
    const short* baseB = Bf + ((size_t)((ptB >> 4) * NCH) * 64 + q * 16 + (ptB & 15)) * 8;
    f32x4 acc = (f32x4){0.f, 0.f, 0.f, 0.f};
    #pragma unroll
    for (int c = 0; c < NCH; ++c) {
        short8 a = *(const short8*)(baseA + c * 512);
        short8 b = *(const short8*)(baseB + c * 512);
        acc = __builtin_amdgcn_mfma_f32_16x16x32_bf16(a, b, acc, 0, 0, 0);
    }
    // C layout: row = q*4+reg, col = lane&15.  Extract S[a<5][b<5].
    if (lane < 5) {
        #pragma unroll
        for (int reg = 0; reg < 4; ++reg) sbuf[w4][reg * 5 + lane] = acc[reg];
    }
    if (lane >= 16 && lane < 21) sbuf[w4][20 + (lane - 16)] = acc[0];
    __syncthreads();
    if (lane == 0) {
        float S[25];
        #pragma unroll
        for (int a = 0; a < 5; ++a) {
            float va = val1[i * NS + a];
            #pragma unroll
            for (int b = 0; b < 5; ++b) {
                float vb = val2[j * NS + b];
                S[a * 5 + b] = (va != 0.0f && vb != 0.0f) ? sbuf[w4][a * 5 + b] : -1.0f;
            }
        }
        float M1[25], M2[25];
        if (!dir) {
            #pragma unroll
            for (int x = 0; x < 5; ++x)
                #pragma unroll
                for (int y = 0; y < 5; ++y) {
                    M1[x * 5 + y] = S[x * 5 + y];
                    M2[x * 5 + y] = S[x * 5 + (4 - y)];
                }
        } else {
            #pragma unroll
            for (int x = 0; x < 5; ++x)
                #pragma unroll
                for (int y = 0; y < 5; ++y) {
                    M1[x * 5 + y] = S[y * 5 + x];
                    M2[x * 5 + y] = S[(4 - y) * 5 + x];
                }
        }
        float n1 = nw5(M1);
        float n2 = nw5(M2);
        if (!dir) { nwout[row * 20 + r] = n1; nwout[row * 20 + 10 + r] = n2; }
        else      { nw2buf[row * 20 + r] = n1; nw2buf[row * 20 + 10 + r] = n2; }
    }
}

// ---------------- K3c: argmax over 20 + mutual check ----------------------
__global__ void argmax_kernel(const float* __restrict__ nw1, const float* __restrict__ nw2,
                              const int* __restrict__ topk1, const int* __restrict__ topk2,
                              int* __restrict__ mpre, int* __restrict__ m2) {
    int t = blockIdx.x * 256 + threadIdx.x;
    if (t >= 2400) return;
    int dir = t / NLINES, row = t - dir * NLINES;
    const float* nw = (dir ? nw2 : nw1) + row * 20;
    float best = nw[0]; int bi = 0;
    #pragma unroll
    for (int q = 1; q < 20; ++q) {
        float v = nw[q];
        if (v > best) { best = v; bi = q; }
    }
    int m = (dir ? topk2 : topk1)[row * 10 + (bi % 10)];
    if (dir) m2[row] = m; else mpre[row] = m;
}

__global__ void final_kernel(const int* __restrict__ mpre, const int* __restrict__ m2,
                             float* __restrict__ out) {
    int i = blockIdx.x * 256 + threadIdx.x;
    if (i >= NLINES) return;
    int m = mpre[i];
    out[i] = (m2[m] == i) ? (float)m : -1.0f;
}

extern "C" void kernel_launch(void* const* d_in, const int* in_sizes, int n_in,
                              void* d_out, int out_size, void* d_ws, size_t ws_size,
                              hipStream_t stream) {
    const float* lseg1 = (const float*)d_in[0];
    const float* lseg2 = (const float*)d_in[1];
    const float* desc1 = (const float*)d_in[2];
    const float* desc2 = (const float*)d_in[3];
    float* out = (float*)d_out;

    float* wsf = (float*)d_ws;
    size_t off = 0;
    float* D1 = wsf + off;     off += (size_t)PPAD * DD;
    float* D2 = wsf + off;     off += (size_t)PPAD * DD;
    float* val1 = wsf + off;   off += PPAD;
    float* val2 = wsf + off;   off += PPAD;
    float* lsc = wsf + off;    off += (size_t)NLINES * NLINES;
    float* lscT = wsf + off;   off += (size_t)NLINES * NLINES;
    int* topk1 = (int*)(wsf + off); off += NLINES * 10;
    int* topk2 = (int*)(wsf + off); off += NLINES * 10;
    int* mpre = (int*)(wsf + off);  off += 1280;
    int* m2 = (int*)(wsf + off);    off += 1280;
    float* nw2buf = wsf + off; off += NLINES * 20;
    short* Aext = (short*)(wsf + off); off += (size_t)PPAD * KEXT / 2;
    short* Bext = (short*)(wsf + off); off += (size_t)PPAD * KEXT / 2;
    float* tdesc1 = wsf + off; off += (size_t)HW * DD;
    float* tdesc2 = wsf + off; off += (size_t)HW * DD;
    size_t need_full = off * sizeof(float);
    int use_t = (ws_size >= need_full) ? 1 : 0;

    if (use_t) {
        transpose_desc<<<dim3(HW / 32, DD / 32), dim3(32, 8), 0, stream>>>(desc1, tdesc1);
        transpose_desc<<<dim3(HW / 32, DD / 32), dim3(32, 8), 0, stream>>>(desc2, tdesc2);
    }
    sample_kernel<<<PPAD / 4, 256, 0, stream>>>(lseg1, tdesc1, desc1, D1, val1, use_t);
    sample_kernel<<<PPAD / 4, 256, 0, stream>>>(lseg2, tdesc2, desc2, D2, val2, use_t);

    pack_kernel<<<NGRP, 256, 0, stream>>>(D1, Aext, 1);
    pack_kernel<<<NGRP, 256, 0, stream>>>(D2, Bext, 0);

    score_kernel<<<dim3(NPAD / 32, NPAD / 32), 256, 0, stream>>>(Aext, Bext, val1, val2, lsc);

    transpose_lsc<<<dim3(38, 38), dim3(32, 8), 0, stream>>>(lsc, lscT);

    topk_kernel<<<NLINES, 256, 0, stream>>>(lsc, topk1);
    topk_kernel<<<NLINES, 256, 0, stream>>>(lscT, topk2);

    nw_kernel<<<6000, 256, 0, stream>>>(Aext, Bext, val1, val2, topk1, topk2,
                                        out + NLINES, nw2buf);

    argmax_kernel<<<10, 256, 0, stream>>>(out + NLINES, nw2buf, topk1, topk2, mpre, m2);
    final_kernel<<<5, 256, 0, stream>>>(mpre, m2, out);
}

// Round 6
// 203.233 us; speedup vs baseline: 1.2080x; 1.0271x over previous
//
#include <hip/hip_runtime.h>
#include <hip/hip_bf16.h>

// SOLD2 line matching on MI355X.
// Inputs: line_seg1 (1200,2,2) f32, line_seg2 (1200,2,2) f32,
//         desc1 (1,128,128,128) f32, desc2 (1,128,128,128) f32
// Outputs (concat float32): matches (1200,), nw (1200,20)

#define NLINES 1200
#define NS 5
#define DD 128
#define HH 128
#define WW 128
#define HW (HH*WW)
#define IMGM1 511.0f
#define GAPC 0.1f
#define NPAD 1216          // 38*32
#define PPAD (NPAD*NS)     // 6080 padded points
#define KEXT 384           // 3-term bf16 split: [hi,lo,hi] x [hi,hi,lo]
#define NCH (KEXT/32)      // 12 k-chunks of 32
#define NGRP (PPAD/16)     // 380 16-pt groups

typedef __attribute__((ext_vector_type(8))) short short8;
typedef __attribute__((ext_vector_type(4))) float f32x4;

// ---------------- K0: transpose desc [D][H][W] -> [H*W][D], both sides ----
__global__ void transpose_desc(const float* __restrict__ in1, float* __restrict__ out1,
                               const float* __restrict__ in2, float* __restrict__ out2) {
    const float* in = blockIdx.z ? in2 : in1;
    float* out = blockIdx.z ? out2 : out1;
    __shared__ float t[32][33];
    int s0 = blockIdx.x * 32;          // HW dim
    int d0 = blockIdx.y * 32;          // D dim
    int c = threadIdx.x;               // 0..31
    int r0 = threadIdx.y;              // 0..7
    #pragma unroll
    for (int rr = 0; rr < 32; rr += 8) {
        int d = d0 + r0 + rr;
        t[r0 + rr][c] = in[d * HW + s0 + c];
    }
    __syncthreads();
    #pragma unroll
    for (int rr = 0; rr < 32; rr += 8) {
        int s = s0 + r0 + rr;
        out[s * DD + d0 + c] = t[c][r0 + rr];
    }
}

// ------- K1: fused sample + bilinear + normalize + bf16 split + pack ------
// Block = one 16-pt group of one side. 4 waves, 4 points each (lane=channel).
// Then pack to fragment-major extended operand (coalesced 16B stores).
__global__ void samplepack_kernel(const float* __restrict__ lseg1, const float* __restrict__ lseg2,
                                  const float* __restrict__ tdesc1, const float* __restrict__ tdesc2,
                                  const float* __restrict__ desc1, const float* __restrict__ desc2,
                                  short* __restrict__ Aext, short* __restrict__ Bext,
                                  float* __restrict__ val1, float* __restrict__ val2,
                                  int use_t) {
    int side = blockIdx.y;
    const float* lseg = side ? lseg2 : lseg1;
    const float* tdesc = side ? tdesc2 : tdesc1;
    const float* desc = side ? desc2 : desc1;
    short* Ef = side ? Bext : Aext;
    float* valout = side ? val2 : val1;
    int arole = side ? 0 : 1;          // A: [hi,lo,hi]; B: [hi,hi,lo]

    __shared__ float ds[16][129];
    int g = blockIdx.x;
    int t = threadIdx.x;
    int lane = t & 63, w = t >> 6;

    #pragma unroll
    for (int s = 0; s < 4; ++s) {
        int r = w * 4 + s;
        int pt = g * 16 + r;
        int line = pt / NS;
        int k = pt - line * NS;

        float sy = 0.f, sx = 0.f, ey = 0.f, ex = 0.f;
        if (line < NLINES) {
            sy = lseg[line * 4 + 0]; sx = lseg[line * 4 + 1];
            ey = lseg[line * 4 + 2]; ex = lseg[line * 4 + 3];
        }
        float dy = ey - sy, dx = ex - sx;
        float len = sqrtf(dy * dy + dx * dx);
        float ns = floorf(len * 0.125f);
        ns = fminf(fmaxf(ns, 2.0f), 5.0f);
        float kf = (float)k;
        float validf = (kf < ns) ? 1.0f : 0.0f;
        float py = sy + kf * (dy / (ns - 1.0f));
        float px = sx + kf * (dx / (ns - 1.0f));
        if (validf == 0.0f) { py = 0.0f; px = 0.0f; }

        float xn = 2.0f * px / IMGM1 - 1.0f;
        float yn = 2.0f * py / IMGM1 - 1.0f;
        float ix = ((xn + 1.0f) * (float)WW - 1.0f) * 0.5f;
        float iy = ((yn + 1.0f) * (float)HH - 1.0f) * 0.5f;
        float x0f = floorf(ix), y0f = floorf(iy);
        float wx = ix - x0f, wy = iy - y0f;
        int x0 = (int)x0f, y0 = (int)y0f;

        float w00 = (1.0f - wx) * (1.0f - wy);
        float w10 = wx * (1.0f - wy);
        float w01 = (1.0f - wx) * wy;
        float w11 = wx * wy;

        float v0 = 0.0f, v1 = 0.0f;
        int xs[4] = { x0, x0 + 1, x0,     x0 + 1 };
        int ys[4] = { y0, y0,     y0 + 1, y0 + 1 };
        float ws4[4] = { w00, w10, w01, w11 };
        #pragma unroll
        for (int c = 0; c < 4; ++c) {
            int xi = xs[c], yi = ys[c];
            float inb = (xi >= 0 && xi < WW && yi >= 0 && yi < HH) ? 1.0f : 0.0f;
            int xc = min(max(xi, 0), WW - 1);
            int yc = min(max(yi, 0), HH - 1);
            if (use_t) {
                int base = (yc * WW + xc) * DD;
                v0 += tdesc[base + lane] * inb * ws4[c];
                v1 += tdesc[base + 64 + lane] * inb * ws4[c];
            } else {
                int base = yc * WW + xc;
                v0 += desc[lane * HW + base] * inb * ws4[c];
                v1 += desc[(lane + 64) * HW + base] * inb * ws4[c];
            }
        }
        float ss = v0 * v0 + v1 * v1;
        #pragma unroll
        for (int o = 32; o > 0; o >>= 1) ss += __shfl_xor(ss, o);
        if (ss == 0.0f) ss = 1.0f;   // padding lines: avoid 0/0 NaN
        float nrm = sqrtf(ss);
        ds[r][lane] = v0 / nrm;
        ds[r][64 + lane] = v1 / nrm;
        if (lane == 0) valout[pt] = (line < NLINES) ? validf : 0.0f;
    }
    __syncthreads();

    // pack: Ef block (g,c) is 1024B; lane l=q*16+r holds pt g*16+r,
    // kext = c*32 + q*8 + (0..7)
    #pragma unroll
    for (int it = 0; it < 3; ++it) {
        int idx = it * 256 + t;        // 0..767 = 12 chunks x 64 lanes
        int c = idx >> 6, l = idx & 63;
        int q = l >> 4, r = l & 15;
        short8 outv;
        #pragma unroll
        for (int jj = 0; jj < 8; ++jj) {
            int kext = c * 32 + q * 8 + jj;
            int term = kext >> 7, k = kext & 127;
            float x = ds[r][k];
            __hip_bfloat16 h = __float2bfloat16(x);
            short v = *(short*)&h;
            bool lo_term = arole ? (term == 1) : (term == 2);
            if (lo_term) {
                float hf = __bfloat162float(h);
                __hip_bfloat16 lw = __float2bfloat16(x - hf);
                v = *(short*)&lw;
            }
            outv[jj] = v;
        }
        *(short8*)&Ef[((size_t)(g * NCH + c) * 64 + l) * 8] = outv;
    }
}

// ---------------- K2: MFMA score GEMM + fused per-line-pair reduction -----
// Block: 160x160 points (32x32 lines), 4 waves 2x2, each wave 80x80 via
// 5x5 tiles of mfma_f32_16x16x32_bf16 over KEXT=384 in 12 chunks of 32.
// Single-buffered operand regs + unroll-1 K-loop: ~160 unified regs/wave
// -> 3 waves/SIMD (TLP hides L2 latency). Epilogue writes lsc AND lscT
// (both full-64B-line coalesced).
__launch_bounds__(256, 3)
__global__ void score_kernel(const short* __restrict__ Af, const short* __restrict__ Bf,
                             const float* __restrict__ val1, const float* __restrict__ val2,
                             float* __restrict__ lsc, float* __restrict__ lscT) {
    __shared__ float dump[80 * 161];   // epilogue only (51520 B)

    const int t = threadIdx.x;
    const int lane = t & 63;
    const int w = t >> 6;           // wave 0..3
    const int wm = w >> 1;          // 0..1 row half
    const int wn = w & 1;           // 0..1 col half
    const int gA0 = blockIdx.x * 10;   // first 16-pt group of A side
    const int gB0 = blockIdx.y * 10;

    const short* paw = Af + ((size_t)(gA0 + 5 * wm) * NCH * 64 + lane) * 8;
    const short* pbw = Bf + ((size_t)(gB0 + 5 * wn) * NCH * 64 + lane) * 8;
    // group stride = NCH*512 shorts; chunk stride = 512 shorts

    f32x4 acc[5][5];
    #pragma unroll
    for (int a = 0; a < 5; ++a)
        #pragma unroll
        for (int b = 0; b < 5; ++b)
            acc[a][b] = (f32x4){0.f, 0.f, 0.f, 0.f};

    #pragma unroll 1
    for (int c = 0; c < NCH; ++c) {
        short8 ca[5], cb[5];
        #pragma unroll
        for (int ti = 0; ti < 5; ++ti) {
            ca[ti] = *(const short8*)(paw + ti * (NCH * 512) + c * 512);
            cb[ti] = *(const short8*)(pbw + ti * (NCH * 512) + c * 512);
        }
        #pragma unroll
        for (int ti = 0; ti < 5; ++ti)
            #pragma unroll
            for (int tj = 0; tj < 5; ++tj)
                acc[ti][tj] = __builtin_amdgcn_mfma_f32_16x16x32_bf16(
                    ca[ti], cb[tj], acc[ti][tj], 0, 0, 0);
    }

    // fused epilogue: two phases of 80 rows through LDS, then 5x5 reduction
    const int i0l = blockIdx.x * 32;
    const int j0l = blockIdx.y * 32;
    #pragma unroll
    for (int p = 0; p < 2; ++p) {
        __syncthreads();
        if (wm == p) {
            #pragma unroll
            for (int ti = 0; ti < 5; ++ti) {
                #pragma unroll
                for (int reg = 0; reg < 4; ++reg) {
                    int rloc = 16 * ti + (lane >> 4) * 4 + reg;
                    #pragma unroll
                    for (int tj = 0; tj < 5; ++tj) {
                        int col = 80 * wn + 16 * tj + (lane & 15);
                        dump[rloc * 161 + col] = acc[ti][tj][reg];
                    }
                }
            }
        }
        __syncthreads();
        // pass 1: lsc (32 consecutive j per i -> 2 full lines)
        #pragma unroll
        for (int e = 0; e < 2; ++e) {
            int q = t * 2 + e;            // 0..511 line pairs
            int li = q >> 5, lj = q & 31;
            int i = i0l + 16 * p + li;
            int j = j0l + lj;
            if (i < NLINES && j < NLINES) {
                float S[5][5];
                #pragma unroll
                for (int a = 0; a < 5; ++a) {
                    float va = val1[i * NS + a];
                    #pragma unroll
                    for (int b = 0; b < 5; ++b) {
                        float vb = val2[j * NS + b];
                        float sc = dump[(li * 5 + a) * 161 + (lj * 5 + b)];
                        S[a][b] = (va != 0.0f && vb != 0.0f) ? sc : -1.0f;
                    }
                }
                float sum1 = 0.0f, cnt1 = 0.0f;
                #pragma unroll
                for (int a = 0; a < 5; ++a) {
                    float r = S[a][0];
                    #pragma unroll
                    for (int b = 1; b < 5; ++b) r = fmaxf(r, S[a][b]);
                    float v = (r != -1.0f) ? 1.0f : 0.0f;
                    sum1 += r * v; cnt1 += v;
                }
                float sum2 = 0.0f, cnt2 = 0.0f;
                #pragma unroll
                for (int b = 0; b < 5; ++b) {
                    float r = S[0][b];
                    #pragma unroll
                    for (int a = 1; a < 5; ++a) r = fmaxf(r, S[a][b]);
                    float v = (r != -1.0f) ? 1.0f : 0.0f;
                    sum2 += r * v; cnt2 += v;
                }
                lsc[i * NLINES + j] = (sum1 / cnt1 + sum2 / cnt2) * 0.5f;
            }
        }
        // pass 2: lscT (16 consecutive i per j -> 1 full line)
        #pragma unroll
        for (int e = 0; e < 2; ++e) {
            int q = t * 2 + e;            // 0..511
            int lj = q >> 4, li = q & 15;
            int i = i0l + 16 * p + li;
            int j = j0l + lj;
            if (i < NLINES && j < NLINES) {
                float S[5][5];
                #pragma unroll
                for (int a = 0; a < 5; ++a) {
                    float va = val1[i * NS + a];
                    #pragma unroll
                    for (int b = 0; b < 5; ++b) {
                        float vb = val2[j * NS + b];
                        float sc = dump[(li * 5 + a) * 161 + (lj * 5 + b)];
                        S[a][b] = (va != 0.0f && vb != 0.0f) ? sc : -1.0f;
                    }
                }
                float sum1 = 0.0f, cnt1 = 0.0f;
                #pragma unroll
                for (int a = 0; a < 5; ++a) {
                    float r = S[a][0];
                    #pragma unroll
                    for (int b = 1; b < 5; ++b) r = fmaxf(r, S[a][b]);
                    float v = (r != -1.0f) ? 1.0f : 0.0f;
                    sum1 += r * v; cnt1 += v;
                }
                float sum2 = 0.0f, cnt2 = 0.0f;
                #pragma unroll
                for (int b = 0; b < 5; ++b) {
                    float r = S[0][b];
                    #pragma unroll
                    for (int a = 1; a < 5; ++a) r = fmaxf(r, S[a][b]);
                    float v = (r != -1.0f) ? 1.0f : 0.0f;
                    sum2 += r * v; cnt2 += v;
                }
                lscT[j * NLINES + i] = (sum1 / cnt1 + sum2 / cnt2) * 0.5f;
            }
        }
    }
}

// ------- K3a: per-row top-10 both dirs (stable-argsort tie semantics) -----
__global__ void topk_kernel(const float* __restrict__ lsc, const float* __restrict__ lscT,
                            int* __restrict__ topk1, int* __restrict__ topk2) {
    __shared__ float wv[4];
    __shared__ int wi[4];
    int rb = blockIdx.x;               // 0..2399
    const float* ls = (rb < NLINES) ? (lsc + rb * NLINES) : (lscT + (rb - NLINES) * NLINES);
    int* topk = (rb < NLINES) ? (topk1 + rb * 10) : (topk2 + (rb - NLINES) * 10);
    int t = threadIdx.x;
    int lane = t & 63, w = t >> 6;
    float val[5];
    #pragma unroll
    for (int s = 0; s < 5; ++s) {
        int j = t + 256 * s;
        val[s] = (j < NLINES) ? ls[j] : -1e30f;
    }
    float bv = -1e30f; int bi = -1;
    #pragma unroll
    for (int s = 0; s < 5; ++s) {
        int j = t + 256 * s;
        if (val[s] >= bv) { bv = val[s]; bi = j; }
    }
    for (int sel = 0; sel < 10; ++sel) {
        float rv = bv; int ri = bi;
        #pragma unroll
        for (int o = 32; o > 0; o >>= 1) {
            float ov = __shfl_xor(rv, o);
            int oi = __shfl_xor(ri, o);
            if (ov > rv || (ov == rv && oi > ri)) { rv = ov; ri = oi; }
        }
        if (lane == 0) { wv[w] = rv; wi[w] = ri; }
        __syncthreads();
        float fv = wv[0]; int fi = wi[0];
        #pragma unroll
        for (int qq = 1; qq < 4; ++qq)
            if (wv[qq] > fv || (wv[qq] == fv && wi[qq] > fi)) { fv = wv[qq]; fi = wi[qq]; }
        if (t == 0) topk[9 - sel] = fi;
        if ((fi & 255) == t) {
            val[fi >> 8] = -1e30f;
            bv = -1e30f; bi = -1;
            #pragma unroll
            for (int s = 0; s < 5; ++s) {
                int j = t + 256 * s;
                if (val[s] >= bv) { bv = val[s]; bi = j; }
            }
        }
        __syncthreads();
    }
}

// ---------------- K3b: Needleman-Wunsch via one masked MFMA per pair ------
__device__ __forceinline__ float nw5(const float* M) {
    float F[6] = {0, 0, 0, 0, 0, 0};
    #pragma unroll
    for (int x = 0; x < 5; ++x) {
        float diag = F[0];
        float left = 0.0f;
        #pragma unroll
        for (int y = 1; y <= 5; ++y) {
            float up = F[y];
            float cur = fmaxf(fmaxf(left, up), diag + (M[x * 5 + y - 1] - GAPC));
            F[y] = cur; left = cur; diag = up;
        }
    }
    return F[5];
}

__global__ void nw_kernel(const short* __restrict__ Af, const short* __restrict__ Bf,
                          const float* __restrict__ val1, const float* __restrict__ val2,
                          const int* __restrict__ topk1, const int* __restrict__ topk2,
                          float* __restrict__ nwout, float* __restrict__ nw2buf) {
    __shared__ float sbuf[4][25];
    int w4 = threadIdx.x >> 6;              // wave in block
    int gw = blockIdx.x * 4 + w4;           // 0..23999
    int lane = threadIdx.x & 63;
    int dir = (gw >= 12000) ? 1 : 0;
    int rem = gw - dir * 12000;
    int row = rem / 10, r = rem - row * 10;
    int i, j;
    if (!dir) { i = row; j = topk1[row * 10 + r]; }
    else      { j = row; i = topk2[row * 10 + r]; }

    int q = lane >> 4, rr = lane & 15;
    int ptA = i * 5 + rr, ptB = j * 5 + rr;
    const short* baseA = Af + ((size_t)((ptA >> 4) * NCH) * 64 + q * 16 + (ptA & 15)) * 8;
    const short* baseB = Bf + ((size_t)((ptB >> 4) * NCH) * 64 + q * 16 + (ptB & 15)) * 8;
    f32x4 acc = (f32x4){0.f, 0.f, 0.f, 0.f};
    #pragma unroll
    for (int c = 0; c < NCH; ++c) {
        short8 a = *(const short8*)(baseA + c * 512);
        short8 b = *(const short8*)(baseB + c * 512);
        acc = __builtin_amdgcn_mfma_f32_16x16x32_bf16(a, b, acc, 0, 0, 0);
    }
    // C layout: row = q*4+reg, col = lane&15.  Extract S[a<5][b<5].
    if (lane < 5) {
        #pragma unroll
        for (int reg = 0; reg < 4; ++reg) sbuf[w4][reg * 5 + lane] = acc[reg];
    }
    if (lane >= 16 && lane < 21) sbuf[w4][20 + (lane - 16)] = acc[0];
    __syncthreads();
    if (lane == 0) {
        float S[25];
        #pragma unroll
        for (int a = 0; a < 5; ++a) {
            float va = val1[i * NS + a];
            #pragma unroll
            for (int b = 0; b < 5; ++b) {
                float vb = val2[j * NS + b];
                S[a * 5 + b] = (va != 0.0f && vb != 0.0f) ? sbuf[w4][a * 5 + b] : -1.0f;
            }
        }
        float M1[25], M2[25];
        if (!dir) {
            #pragma unroll
            for (int x = 0; x < 5; ++x)
                #pragma unroll
                for (int y = 0; y < 5; ++y) {
                    M1[x * 5 + y] = S[x * 5 + y];
                    M2[x * 5 + y] = S[x * 5 + (4 - y)];
                }
        } else {
            #pragma unroll
            for (int x = 0; x < 5; ++x)
                #pragma unroll
                for (int y = 0; y < 5; ++y) {
                    M1[x * 5 + y] = S[y * 5 + x];
                    M2[x * 5 + y] = S[(4 - y) * 5 + x];
                }
        }
        float n1 = nw5(M1);
        float n2 = nw5(M2);
        if (!dir) { nwout[row * 20 + r] = n1; nwout[row * 20 + 10 + r] = n2; }
        else      { nw2buf[row * 20 + r] = n1; nw2buf[row * 20 + 10 + r] = n2; }
    }
}

// ---------------- K3c: argmax over 20 + mutual check (single block) -------
__global__ void argmax_final_kernel(const float* __restrict__ nw1, const float* __restrict__ nw2,
                                    const int* __restrict__ topk1, const int* __restrict__ topk2,
                                    float* __restrict__ out) {
    __shared__ int mpre[NLINES];
    __shared__ int m2[NLINES];
    int t = threadIdx.x;               // 0..1023
    for (int qq = t; qq < 2 * NLINES; qq += 1024) {
        int dir = qq / NLINES, row = qq - dir * NLINES;
        const float* nw = (dir ? nw2 : nw1) + row * 20;
        float best = nw[0]; int bi = 0;
        #pragma unroll
        for (int q = 1; q < 20; ++q) {
            float v = nw[q];
            if (v > best) { best = v; bi = q; }
        }
        int m = (dir ? topk2 : topk1)[row * 10 + (bi % 10)];
        if (dir) m2[row] = m; else mpre[row] = m;
    }
    __syncthreads();
    for (int i = t; i < NLINES; i += 1024) {
        int m = mpre[i];
        out[i] = (m2[m] == i) ? (float)m : -1.0f;
    }
}

extern "C" void kernel_launch(void* const* d_in, const int* in_sizes, int n_in,
                              void* d_out, int out_size, void* d_ws, size_t ws_size,
                              hipStream_t stream) {
    const float* lseg1 = (const float*)d_in[0];
    const float* lseg2 = (const float*)d_in[1];
    const float* desc1 = (const float*)d_in[2];
    const float* desc2 = (const float*)d_in[3];
    float* out = (float*)d_out;

    float* wsf = (float*)d_ws;
    size_t off = 0;
    float* val1 = wsf + off;   off += PPAD;
    float* val2 = wsf + off;   off += PPAD;
    float* lsc = wsf + off;    off += (size_t)NLINES * NLINES;
    float* lscT = wsf + off;   off += (size_t)NLINES * NLINES;
    int* topk1 = (int*)(wsf + off); off += NLINES * 10;
    int* topk2 = (int*)(wsf + off); off += NLINES * 10;
    float* nw2buf = wsf + off; off += NLINES * 20;
    short* Aext = (short*)(wsf + off); off += (size_t)PPAD * KEXT / 2;
    short* Bext = (short*)(wsf + off); off += (size_t)PPAD * KEXT / 2;
    float* tdesc1 = wsf + off; off += (size_t)HW * DD;
    float* tdesc2 = wsf + off; off += (size_t)HW * DD;
    size_t need_full = off * sizeof(float);
    int use_t = (ws_size >= need_full) ? 1 : 0;

    if (use_t) {
        transpose_desc<<<dim3(HW / 32, DD / 32, 2), dim3(32, 8), 0, stream>>>(
            desc1, tdesc1, desc2, tdesc2);
    }
    samplepack_kernel<<<dim3(NGRP, 2), 256, 0, stream>>>(
        lseg1, lseg2, tdesc1, tdesc2, desc1, desc2, Aext, Bext, val1, val2, use_t);

    score_kernel<<<dim3(NPAD / 32, NPAD / 32), 256, 0, stream>>>(Aext, Bext, val1, val2,
                                                                 lsc, lscT);

    topk_kernel<<<2 * NLINES, 256, 0, stream>>>(lsc, lscT, topk1, topk2);

    nw_kernel<<<6000, 256, 0, stream>>>(Aext, Bext, val1, val2, topk1, topk2,
                                        out + NLINES, nw2buf);

    argmax_final_kernel<<<1, 1024, 0, stream>>>(out + NLINES, nw2buf, topk1, topk2, out);
}

// Round 7
// 197.642 us; speedup vs baseline: 1.2422x; 1.0283x over previous
//
#include <hip/hip_runtime.h>
#include <hip/hip_bf16.h>

// SOLD2 line matching on MI355X.
// Inputs: line_seg1 (1200,2,2) f32, line_seg2 (1200,2,2) f32,
//         desc1 (1,128,128,128) f32, desc2 (1,128,128,128) f32
// Outputs (concat float32): matches (1200,), nw (1200,20)

#define NLINES 1200
#define NS 5
#define DD 128
#define HH 128
#define WW 128
#define HW (HH*WW)
#define IMGM1 511.0f
#define GAPC 0.1f
#define NPAD 1216          // 38*32
#define PPAD (NPAD*NS)     // 6080 padded points
#define KEXT 384           // 3-term bf16 split: [hi,lo,hi] x [hi,hi,lo]
#define NCH (KEXT/32)      // 12 k-chunks of 32
#define NGRP (PPAD/16)     // 380 16-pt groups

typedef __attribute__((ext_vector_type(8))) short short8;
typedef __attribute__((ext_vector_type(4))) float f32x4;

// ---------------- K0: transpose desc [D][H][W] -> [H*W][D], both sides ----
__global__ void transpose_desc(const float* __restrict__ in1, float* __restrict__ out1,
                               const float* __restrict__ in2, float* __restrict__ out2) {
    const float* in = blockIdx.z ? in2 : in1;
    float* out = blockIdx.z ? out2 : out1;
    __shared__ float t[32][33];
    int s0 = blockIdx.x * 32;          // HW dim
    int d0 = blockIdx.y * 32;          // D dim
    int c = threadIdx.x;               // 0..31
    int r0 = threadIdx.y;              // 0..7
    #pragma unroll
    for (int rr = 0; rr < 32; rr += 8) {
        int d = d0 + r0 + rr;
        t[r0 + rr][c] = in[d * HW + s0 + c];
    }
    __syncthreads();
    #pragma unroll
    for (int rr = 0; rr < 32; rr += 8) {
        int s = s0 + r0 + rr;
        out[s * DD + d0 + c] = t[c][r0 + rr];
    }
}

// ------- K1: fused sample + bilinear + normalize + bf16 split + pack ------
__global__ void samplepack_kernel(const float* __restrict__ lseg1, const float* __restrict__ lseg2,
                                  const float* __restrict__ tdesc1, const float* __restrict__ tdesc2,
                                  const float* __restrict__ desc1, const float* __restrict__ desc2,
                                  short* __restrict__ Aext, short* __restrict__ Bext,
                                  float* __restrict__ val1, float* __restrict__ val2,
                                  int use_t) {
    int side = blockIdx.y;
    const float* lseg = side ? lseg2 : lseg1;
    const float* tdesc = side ? tdesc2 : tdesc1;
    const float* desc = side ? desc2 : desc1;
    short* Ef = side ? Bext : Aext;
    float* valout = side ? val2 : val1;
    int arole = side ? 0 : 1;          // A: [hi,lo,hi]; B: [hi,hi,lo]

    __shared__ float ds[16][129];
    int g = blockIdx.x;
    int t = threadIdx.x;
    int lane = t & 63, w = t >> 6;

    #pragma unroll
    for (int s = 0; s < 4; ++s) {
        int r = w * 4 + s;
        int pt = g * 16 + r;
        int line = pt / NS;
        int k = pt - line * NS;

        float sy = 0.f, sx = 0.f, ey = 0.f, ex = 0.f;
        if (line < NLINES) {
            sy = lseg[line * 4 + 0]; sx = lseg[line * 4 + 1];
            ey = lseg[line * 4 + 2]; ex = lseg[line * 4 + 3];
        }
        float dy = ey - sy, dx = ex - sx;
        float len = sqrtf(dy * dy + dx * dx);
        float ns = floorf(len * 0.125f);
        ns = fminf(fmaxf(ns, 2.0f), 5.0f);
        float kf = (float)k;
        float validf = (kf < ns) ? 1.0f : 0.0f;
        float py = sy + kf * (dy / (ns - 1.0f));
        float px = sx + kf * (dx / (ns - 1.0f));
        if (validf == 0.0f) { py = 0.0f; px = 0.0f; }

        float xn = 2.0f * px / IMGM1 - 1.0f;
        float yn = 2.0f * py / IMGM1 - 1.0f;
        float ix = ((xn + 1.0f) * (float)WW - 1.0f) * 0.5f;
        float iy = ((yn + 1.0f) * (float)HH - 1.0f) * 0.5f;
        float x0f = floorf(ix), y0f = floorf(iy);
        float wx = ix - x0f, wy = iy - y0f;
        int x0 = (int)x0f, y0 = (int)y0f;

        float w00 = (1.0f - wx) * (1.0f - wy);
        float w10 = wx * (1.0f - wy);
        float w01 = (1.0f - wx) * wy;
        float w11 = wx * wy;

        float v0 = 0.0f, v1 = 0.0f;
        int xs[4] = { x0, x0 + 1, x0,     x0 + 1 };
        int ys[4] = { y0, y0,     y0 + 1, y0 + 1 };
        float ws4[4] = { w00, w10, w01, w11 };
        #pragma unroll
        for (int c = 0; c < 4; ++c) {
            int xi = xs[c], yi = ys[c];
            float inb = (xi >= 0 && xi < WW && yi >= 0 && yi < HH) ? 1.0f : 0.0f;
            int xc = min(max(xi, 0), WW - 1);
            int yc = min(max(yi, 0), HH - 1);
            if (use_t) {
                int base = (yc * WW + xc) * DD;
                v0 += tdesc[base + lane] * inb * ws4[c];
                v1 += tdesc[base + 64 + lane] * inb * ws4[c];
            } else {
                int base = yc * WW + xc;
                v0 += desc[lane * HW + base] * inb * ws4[c];
                v1 += desc[(lane + 64) * HW + base] * inb * ws4[c];
            }
        }
        float ss = v0 * v0 + v1 * v1;
        #pragma unroll
        for (int o = 32; o > 0; o >>= 1) ss += __shfl_xor(ss, o);
        if (ss == 0.0f) ss = 1.0f;   // padding lines: avoid 0/0 NaN
        float nrm = sqrtf(ss);
        ds[r][lane] = v0 / nrm;
        ds[r][64 + lane] = v1 / nrm;
        if (lane == 0) valout[pt] = (line < NLINES) ? validf : 0.0f;
    }
    __syncthreads();

    #pragma unroll
    for (int it = 0; it < 3; ++it) {
        int idx = it * 256 + t;        // 0..767 = 12 chunks x 64 lanes
        int c = idx >> 6, l = idx & 63;
        int q = l >> 4, r = l & 15;
        short8 outv;
        #pragma unroll
        for (int jj = 0; jj < 8; ++jj) {
            int kext = c * 32 + q * 8 + jj;
            int term = kext >> 7, k = kext & 127;
            float x = ds[r][k];
            __hip_bfloat16 h = __float2bfloat16(x);
            short v = *(short*)&h;
            bool lo_term = arole ? (term == 1) : (term == 2);
            if (lo_term) {
                float hf = __bfloat162float(h);
                __hip_bfloat16 lw = __float2bfloat16(x - hf);
                v = *(short*)&lw;
            }
            outv[jj] = v;
        }
        *(short8*)&Ef[((size_t)(g * NCH + c) * 64 + l) * 8] = outv;
    }
}

// ---------------- K2: MFMA score GEMM + fused per-line-pair reduction -----
// R5's double-buffered direct-global K-loop (proven fastest) + dual output.
__launch_bounds__(256, 2)
__global__ void score_kernel(const short* __restrict__ Af, const short* __restrict__ Bf,
                             const float* __restrict__ val1, const float* __restrict__ val2,
                             float* __restrict__ lsc, float* __restrict__ lscT) {
    __shared__ float dump[80 * 161];   // epilogue only (51520 B)

    const int t = threadIdx.x;
    const int lane = t & 63;
    const int w = t >> 6;           // wave 0..3
    const int wm = w >> 1;          // 0..1 row half
    const int wn = w & 1;           // 0..1 col half
    const int gA0 = blockIdx.x * 10;   // first 16-pt group of A side
    const int gB0 = blockIdx.y * 10;

    const short* pa[5];
    const short* pb[5];
    #pragma unroll
    for (int ti = 0; ti < 5; ++ti) {
        pa[ti] = Af + ((size_t)(gA0 + 5 * wm + ti) * NCH * 64 + lane) * 8;
        pb[ti] = Bf + ((size_t)(gB0 + 5 * wn + ti) * NCH * 64 + lane) * 8;
    }

    f32x4 acc[5][5];
    #pragma unroll
    for (int a = 0; a < 5; ++a)
        #pragma unroll
        for (int b = 0; b < 5; ++b)
            acc[a][b] = (f32x4){0.f, 0.f, 0.f, 0.f};

    short8 ca[5], cb[5], na[5], nb[5];
    #pragma unroll
    for (int ti = 0; ti < 5; ++ti) {
        ca[ti] = *(const short8*)(pa[ti]);
        cb[ti] = *(const short8*)(pb[ti]);
    }
    #pragma unroll
    for (int c = 0; c < NCH; c += 2) {
        #pragma unroll
        for (int ti = 0; ti < 5; ++ti) {
            na[ti] = *(const short8*)(pa[ti] + (c + 1) * 512);
            nb[ti] = *(const short8*)(pb[ti] + (c + 1) * 512);
        }
        #pragma unroll
        for (int ti = 0; ti < 5; ++ti)
            #pragma unroll
            for (int tj = 0; tj < 5; ++tj)
                acc[ti][tj] = __builtin_amdgcn_mfma_f32_16x16x32_bf16(
                    ca[ti], cb[tj], acc[ti][tj], 0, 0, 0);
        if (c + 2 < NCH) {
            #pragma unroll
            for (int ti = 0; ti < 5; ++ti) {
                ca[ti] = *(const short8*)(pa[ti] + (c + 2) * 512);
                cb[ti] = *(const short8*)(pb[ti] + (c + 2) * 512);
            }
        }
        #pragma unroll
        for (int ti = 0; ti < 5; ++ti)
            #pragma unroll
            for (int tj = 0; tj < 5; ++tj)
                acc[ti][tj] = __builtin_amdgcn_mfma_f32_16x16x32_bf16(
                    na[ti], nb[tj], acc[ti][tj], 0, 0, 0);
    }

    // fused epilogue: two phases of 80 rows through LDS, then 5x5 reduction
    const int i0l = blockIdx.x * 32;
    const int j0l = blockIdx.y * 32;
    #pragma unroll
    for (int p = 0; p < 2; ++p) {
        __syncthreads();
        if (wm == p) {
            #pragma unroll
            for (int ti = 0; ti < 5; ++ti) {
                #pragma unroll
                for (int reg = 0; reg < 4; ++reg) {
                    int rloc = 16 * ti + (lane >> 4) * 4 + reg;
                    #pragma unroll
                    for (int tj = 0; tj < 5; ++tj) {
                        int col = 80 * wn + 16 * tj + (lane & 15);
                        dump[rloc * 161 + col] = acc[ti][tj][reg];
                    }
                }
            }
        }
        __syncthreads();
        // pass 1: lsc (coalesced in j)
        #pragma unroll
        for (int e = 0; e < 2; ++e) {
            int q = t * 2 + e;
            int li = q >> 5, lj = q & 31;
            int i = i0l + 16 * p + li;
            int j = j0l + lj;
            if (i < NLINES && j < NLINES) {
                float S[5][5];
                #pragma unroll
                for (int a = 0; a < 5; ++a) {
                    float va = val1[i * NS + a];
                    #pragma unroll
                    for (int b = 0; b < 5; ++b) {
                        float vb = val2[j * NS + b];
                        float sc = dump[(li * 5 + a) * 161 + (lj * 5 + b)];
                        S[a][b] = (va != 0.0f && vb != 0.0f) ? sc : -1.0f;
                    }
                }
                float sum1 = 0.0f, cnt1 = 0.0f;
                #pragma unroll
                for (int a = 0; a < 5; ++a) {
                    float r = S[a][0];
                    #pragma unroll
                    for (int b = 1; b < 5; ++b) r = fmaxf(r, S[a][b]);
                    float v = (r != -1.0f) ? 1.0f : 0.0f;
                    sum1 += r * v; cnt1 += v;
                }
                float sum2 = 0.0f, cnt2 = 0.0f;
                #pragma unroll
                for (int b = 0; b < 5; ++b) {
                    float r = S[0][b];
                    #pragma unroll
                    for (int a = 1; a < 5; ++a) r = fmaxf(r, S[a][b]);
                    float v = (r != -1.0f) ? 1.0f : 0.0f;
                    sum2 += r * v; cnt2 += v;
                }
                lsc[i * NLINES + j] = (sum1 / cnt1 + sum2 / cnt2) * 0.5f;
            }
        }
        // pass 2: lscT (coalesced in i)
        #pragma unroll
        for (int e = 0; e < 2; ++e) {
            int q = t * 2 + e;
            int lj = q >> 4, li = q & 15;
            int i = i0l + 16 * p + li;
            int j = j0l + lj;
            if (i < NLINES && j < NLINES) {
                float S[5][5];
                #pragma unroll
                for (int a = 0; a < 5; ++a) {
                    float va = val1[i * NS + a];
                    #pragma unroll
                    for (int b = 0; b < 5; ++b) {
                        float vb = val2[j * NS + b];
                        float sc = dump[(li * 5 + a) * 161 + (lj * 5 + b)];
                        S[a][b] = (va != 0.0f && vb != 0.0f) ? sc : -1.0f;
                    }
                }
                float sum1 = 0.0f, cnt1 = 0.0f;
                #pragma unroll
                for (int a = 0; a < 5; ++a) {
                    float r = S[a][0];
                    #pragma unroll
                    for (int b = 1; b < 5; ++b) r = fmaxf(r, S[a][b]);
                    float v = (r != -1.0f) ? 1.0f : 0.0f;
                    sum1 += r * v; cnt1 += v;
                }
                float sum2 = 0.0f, cnt2 = 0.0f;
                #pragma unroll
                for (int b = 0; b < 5; ++b) {
                    float r = S[0][b];
                    #pragma unroll
                    for (int a = 1; a < 5; ++a) r = fmaxf(r, S[a][b]);
                    float v = (r != -1.0f) ? 1.0f : 0.0f;
                    sum2 += r * v; cnt2 += v;
                }
                lscT[j * NLINES + i] = (sum1 / cnt1 + sum2 / cnt2) * 0.5f;
            }
        }
    }
}

// ------- K3a: per-row top-10 both dirs (stable-argsort tie semantics) -----
__global__ void topk_kernel(const float* __restrict__ lsc, const float* __restrict__ lscT,
                            int* __restrict__ topk1, int* __restrict__ topk2) {
    __shared__ float wv[4];
    __shared__ int wi[4];
    int rb = blockIdx.x;               // 0..2399
    const float* ls = (rb < NLINES) ? (lsc + rb * NLINES) : (lscT + (rb - NLINES) * NLINES);
    int* topk = (rb < NLINES) ? (topk1 + rb * 10) : (topk2 + (rb - NLINES) * 10);
    int t = threadIdx.x;
    int lane = t & 63, w = t >> 6;
    float val[5];
    #pragma unroll
    for (int s = 0; s < 5; ++s) {
        int j = t + 256 * s;
        val[s] = (j < NLINES) ? ls[j] : -1e30f;
    }
    float bv = -1e30f; int bi = -1;
    #pragma unroll
    for (int s = 0; s < 5; ++s) {
        int j = t + 256 * s;
        if (val[s] >= bv) { bv = val[s]; bi = j; }
    }
    for (int sel = 0; sel < 10; ++sel) {
        float rv = bv; int ri = bi;
        #pragma unroll
        for (int o = 32; o > 0; o >>= 1) {
            float ov = __shfl_xor(rv, o);
            int oi = __shfl_xor(ri, o);
            if (ov > rv || (ov == rv && oi > ri)) { rv = ov; ri = oi; }
        }
        if (lane == 0) { wv[w] = rv; wi[w] = ri; }
        __syncthreads();
        float fv = wv[0]; int fi = wi[0];
        #pragma unroll
        for (int qq = 1; qq < 4; ++qq)
            if (wv[qq] > fv || (wv[qq] == fv && wi[qq] > fi)) { fv = wv[qq]; fi = wi[qq]; }
        if (t == 0) topk[9 - sel] = fi;
        if ((fi & 255) == t) {
            val[fi >> 8] = -1e30f;
            bv = -1e30f; bi = -1;
            #pragma unroll
            for (int s = 0; s < 5; ++s) {
                int j = t + 256 * s;
                if (val[s] >= bv) { bv = val[s]; bi = j; }
            }
        }
        __syncthreads();
    }
}

// ---------------- K3b: NW, one row per 64-thread block --------------------
// Shared line's 12 fragment chunks preloaded to regs; two candidate lines
// packed per MFMA (rows/cols 0-4 and 8-12); nw5 DP spread over 20 lanes.
__device__ __forceinline__ float nw5(const float* M) {
    float F[6] = {0, 0, 0, 0, 0, 0};
    #pragma unroll
    for (int x = 0; x < 5; ++x) {
        float diag = F[0];
        float left = 0.0f;
        #pragma unroll
        for (int y = 1; y <= 5; ++y) {
            float up = F[y];
            float cur = fmaxf(fmaxf(left, up), diag + (M[x * 5 + y - 1] - GAPC));
            F[y] = cur; left = cur; diag = up;
        }
    }
    return F[5];
}

__global__ void nw_kernel(const short* __restrict__ Af, const short* __restrict__ Bf,
                          const float* __restrict__ val1, const float* __restrict__ val2,
                          const int* __restrict__ topk1, const int* __restrict__ topk2,
                          float* __restrict__ nwout, float* __restrict__ nw2buf) {
    __shared__ float sbuf[10][25];
    __shared__ int jl[10];
    int rb = blockIdx.x;                    // 0..2399
    int dir = (rb >= NLINES) ? 1 : 0;
    int row = rb - dir * NLINES;
    int lane = threadIdx.x;                 // 0..63
    int q = lane >> 4, rr = lane & 15;

    if (lane < 10) jl[lane] = (dir ? topk2 : topk1)[row * 10 + lane];
    __syncthreads();

    const short* shEf = dir ? Bf : Af;      // shared side
    const short* cdEf = dir ? Af : Bf;      // candidate side

    // preload shared line fragments (rows 0-4 = its 5 pts, 5-15 clamped)
    int ptS = row * 5 + min(rr, 4);
    const short* shp = shEf + ((size_t)(ptS >> 4) * NCH * 64 + q * 16 + (ptS & 15)) * 8;
    short8 sh[NCH];
    #pragma unroll
    for (int c = 0; c < NCH; ++c) sh[c] = *(const short8*)(shp + c * 512);

    #pragma unroll
    for (int pp = 0; pp < 5; ++pp) {
        int c1 = jl[2 * pp], c2 = jl[2 * pp + 1];
        int ptC = (rr < 8) ? (c1 * 5 + min(rr, 4)) : (c2 * 5 + min(rr - 8, 4));
        const short* cp = cdEf + ((size_t)(ptC >> 4) * NCH * 64 + q * 16 + (ptC & 15)) * 8;
        f32x4 acc = (f32x4){0.f, 0.f, 0.f, 0.f};
        #pragma unroll
        for (int c = 0; c < NCH; ++c) {
            short8 cb = *(const short8*)(cp + c * 512);
            acc = dir ? __builtin_amdgcn_mfma_f32_16x16x32_bf16(cb, sh[c], acc, 0, 0, 0)
                      : __builtin_amdgcn_mfma_f32_16x16x32_bf16(sh[c], cb, acc, 0, 0, 0);
        }
        // C layout: m = q*4+reg, n = lane&15
        #pragma unroll
        for (int reg = 0; reg < 4; ++reg) {
            int m = q * 4 + reg, n = rr;
            if (!dir) {
                if (m < 5 && n < 5) sbuf[2 * pp][m * 5 + n] = acc[reg];
                if (m < 5 && n >= 8 && n < 13) sbuf[2 * pp + 1][m * 5 + (n - 8)] = acc[reg];
            } else {
                if (m < 5 && n < 5) sbuf[2 * pp][m * 5 + n] = acc[reg];
                if (m >= 8 && m < 13 && n < 5) sbuf[2 * pp + 1][(m - 8) * 5 + n] = acc[reg];
            }
        }
    }
    __syncthreads();

    if (lane < 20) {
        int r = lane >> 1, rev = lane & 1;
        int i = dir ? jl[r] : row;
        int j = dir ? row : jl[r];
        float S[25];
        #pragma unroll
        for (int a = 0; a < 5; ++a) {
            float va = val1[i * NS + a];
            #pragma unroll
            for (int b = 0; b < 5; ++b) {
                float vb = val2[j * NS + b];
                S[a * 5 + b] = (va != 0.0f && vb != 0.0f) ? sbuf[r][a * 5 + b] : -1.0f;
            }
        }
        float M[25];
        #pragma unroll
        for (int x = 0; x < 5; ++x)
            #pragma unroll
            for (int y = 0; y < 5; ++y) {
                if (!dir) M[x * 5 + y] = rev ? S[x * 5 + (4 - y)] : S[x * 5 + y];
                else      M[x * 5 + y] = rev ? S[(4 - y) * 5 + x] : S[y * 5 + x];
            }
        float nwv = nw5(M);
        float* o = dir ? nw2buf : nwout;
        o[row * 20 + rev * 10 + r] = nwv;
    }
}

// ---------------- K3c: argmax over 20 + mutual check (single block) -------
__global__ void argmax_final_kernel(const float* __restrict__ nw1, const float* __restrict__ nw2,
                                    const int* __restrict__ topk1, const int* __restrict__ topk2,
                                    float* __restrict__ out) {
    __shared__ int mpre[NLINES];
    __shared__ int m2[NLINES];
    int t = threadIdx.x;               // 0..1023
    for (int qq = t; qq < 2 * NLINES; qq += 1024) {
        int dir = qq / NLINES, row = qq - dir * NLINES;
        const float* nw = (dir ? nw2 : nw1) + row * 20;
        float best = nw[0]; int bi = 0;
        #pragma unroll
        for (int q = 1; q < 20; ++q) {
            float v = nw[q];
            if (v > best) { best = v; bi = q; }
        }
        int m = (dir ? topk2 : topk1)[row * 10 + (bi % 10)];
        if (dir) m2[row] = m; else mpre[row] = m;
    }
    __syncthreads();
    for (int i = t; i < NLINES; i += 1024) {
        int m = mpre[i];
        out[i] = (m2[m] == i) ? (float)m : -1.0f;
    }
}

extern "C" void kernel_launch(void* const* d_in, const int* in_sizes, int n_in,
                              void* d_out, int out_size, void* d_ws, size_t ws_size,
                              hipStream_t stream) {
    const float* lseg1 = (const float*)d_in[0];
    const float* lseg2 = (const float*)d_in[1];
    const float* desc1 = (const float*)d_in[2];
    const float* desc2 = (const float*)d_in[3];
    float* out = (float*)d_out;

    float* wsf = (float*)d_ws;
    size_t off = 0;
    float* val1 = wsf + off;   off += PPAD;
    float* val2 = wsf + off;   off += PPAD;
    float* lsc = wsf + off;    off += (size_t)NLINES * NLINES;
    float* lscT = wsf + off;   off += (size_t)NLINES * NLINES;
    int* topk1 = (int*)(wsf + off); off += NLINES * 10;
    int* topk2 = (int*)(wsf + off); off += NLINES * 10;
    float* nw2buf = wsf + off; off += NLINES * 20;
    short* Aext = (short*)(wsf + off); off += (size_t)PPAD * KEXT / 2;
    short* Bext = (short*)(wsf + off); off += (size_t)PPAD * KEXT / 2;
    float* tdesc1 = wsf + off; off += (size_t)HW * DD;
    float* tdesc2 = wsf + off; off += (size_t)HW * DD;
    size_t need_full = off * sizeof(float);
    int use_t = (ws_size >= need_full) ? 1 : 0;

    if (use_t) {
        transpose_desc<<<dim3(HW / 32, DD / 32, 2), dim3(32, 8), 0, stream>>>(
            desc1, tdesc1, desc2, tdesc2);
    }
    samplepack_kernel<<<dim3(NGRP, 2), 256, 0, stream>>>(
        lseg1, lseg2, tdesc1, tdesc2, desc1, desc2, Aext, Bext, val1, val2, use_t);

    score_kernel<<<dim3(NPAD / 32, NPAD / 32), 256, 0, stream>>>(Aext, Bext, val1, val2,
                                                                 lsc, lscT);

    topk_kernel<<<2 * NLINES, 256, 0, stream>>>(lsc, lscT, topk1, topk2);

    nw_kernel<<<2 * NLINES, 64, 0, stream>>>(Aext, Bext, val1, val2, topk1, topk2,
                                             out + NLINES, nw2buf);

    argmax_final_kernel<<<1, 1024, 0, stream>>>(out + NLINES, nw2buf, topk1, topk2, out);
}

// Round 8
// 183.013 us; speedup vs baseline: 1.3415x; 1.0799x over previous
//
#include <hip/hip_runtime.h>
#include <hip/hip_bf16.h>

// SOLD2 line matching on MI355X.
// Inputs: line_seg1 (1200,2,2) f32, line_seg2 (1200,2,2) f32,
//         desc1 (1,128,128,128) f32, desc2 (1,128,128,128) f32
// Outputs (concat float32): matches (1200,), nw (1200,20)

#define NLINES 1200
#define NS 5
#define DD 128
#define HH 128
#define WW 128
#define HW (HH*WW)
#define IMGM1 511.0f
#define GAPC 0.1f
#define NPAD 1216          // 38*32
#define PPAD (NPAD*NS)     // 6080 padded points
#define KEXT 384           // 3-term bf16 split: [hi,lo,hi] x [hi,hi,lo]
#define NCH (KEXT/32)      // 12 k-chunks of 32
#define NGRP (PPAD/16)     // 380 16-pt groups

typedef __attribute__((ext_vector_type(8))) short short8;
typedef __attribute__((ext_vector_type(4))) float f32x4;

// ------ K0: transpose desc [D][H][W] -> [H*W][D], float4 both ways --------
// Block: 32 d x 128 s tile, 256 threads.
__global__ void transpose_desc(const float* __restrict__ in1, float* __restrict__ out1,
                               const float* __restrict__ in2, float* __restrict__ out2) {
    const float* in = blockIdx.z ? in2 : in1;
    float* out = blockIdx.z ? out2 : out1;
    __shared__ float t[32][132];
    int s0 = blockIdx.x * 128;         // HW dim
    int d0 = blockIdx.y * 32;          // D dim
    int tid = threadIdx.x;
    #pragma unroll
    for (int pass = 0; pass < 4; ++pass) {
        int idx = pass * 256 + tid;    // 0..1023 = 32 d x 32 s-chunks
        int dr = idx >> 5, si = idx & 31;
        float4 v = *(const float4*)&in[(size_t)(d0 + dr) * HW + s0 + 4 * si];
        *(float4*)&t[dr][4 * si] = v;
    }
    __syncthreads();
    #pragma unroll
    for (int pass = 0; pass < 4; ++pass) {
        int idx = pass * 256 + tid;    // 0..1023 = 128 s x 8 d-chunks
        int sr = idx >> 3, di = idx & 7;
        float4 v = { t[4 * di][sr], t[4 * di + 1][sr], t[4 * di + 2][sr], t[4 * di + 3][sr] };
        *(float4*)&out[(size_t)(s0 + sr) * DD + d0 + 4 * di] = v;
    }
}

// ------- K1: fused sample + bilinear + normalize + bf16 split + pack ------
__global__ void samplepack_kernel(const float* __restrict__ lseg1, const float* __restrict__ lseg2,
                                  const float* __restrict__ tdesc1, const float* __restrict__ tdesc2,
                                  const float* __restrict__ desc1, const float* __restrict__ desc2,
                                  short* __restrict__ Aext, short* __restrict__ Bext,
                                  float* __restrict__ val1, float* __restrict__ val2,
                                  int use_t) {
    int side = blockIdx.y;
    const float* lseg = side ? lseg2 : lseg1;
    const float* tdesc = side ? tdesc2 : tdesc1;
    const float* desc = side ? desc2 : desc1;
    short* Ef = side ? Bext : Aext;
    float* valout = side ? val2 : val1;
    int arole = side ? 0 : 1;          // A: [hi,lo,hi]; B: [hi,hi,lo]

    __shared__ float ds[16][129];
    int g = blockIdx.x;
    int t = threadIdx.x;
    int lane = t & 63, w = t >> 6;

    #pragma unroll
    for (int s = 0; s < 4; ++s) {
        int r = w * 4 + s;
        int pt = g * 16 + r;
        int line = pt / NS;
        int k = pt - line * NS;

        float sy = 0.f, sx = 0.f, ey = 0.f, ex = 0.f;
        if (line < NLINES) {
            sy = lseg[line * 4 + 0]; sx = lseg[line * 4 + 1];
            ey = lseg[line * 4 + 2]; ex = lseg[line * 4 + 3];
        }
        float dy = ey - sy, dx = ex - sx;
        float len = sqrtf(dy * dy + dx * dx);
        float ns = floorf(len * 0.125f);
        ns = fminf(fmaxf(ns, 2.0f), 5.0f);
        float kf = (float)k;
        float validf = (kf < ns) ? 1.0f : 0.0f;
        float py = sy + kf * (dy / (ns - 1.0f));
        float px = sx + kf * (dx / (ns - 1.0f));
        if (validf == 0.0f) { py = 0.0f; px = 0.0f; }

        float xn = 2.0f * px / IMGM1 - 1.0f;
        float yn = 2.0f * py / IMGM1 - 1.0f;
        float ix = ((xn + 1.0f) * (float)WW - 1.0f) * 0.5f;
        float iy = ((yn + 1.0f) * (float)HH - 1.0f) * 0.5f;
        float x0f = floorf(ix), y0f = floorf(iy);
        float wx = ix - x0f, wy = iy - y0f;
        int x0 = (int)x0f, y0 = (int)y0f;

        float w00 = (1.0f - wx) * (1.0f - wy);
        float w10 = wx * (1.0f - wy);
        float w01 = (1.0f - wx) * wy;
        float w11 = wx * wy;

        float v0 = 0.0f, v1 = 0.0f;
        int xs[4] = { x0, x0 + 1, x0,     x0 + 1 };
        int ys[4] = { y0, y0,     y0 + 1, y0 + 1 };
        float ws4[4] = { w00, w10, w01, w11 };
        #pragma unroll
        for (int c = 0; c < 4; ++c) {
            int xi = xs[c], yi = ys[c];
            float inb = (xi >= 0 && xi < WW && yi >= 0 && yi < HH) ? 1.0f : 0.0f;
            int xc = min(max(xi, 0), WW - 1);
            int yc = min(max(yi, 0), HH - 1);
            if (use_t) {
                int base = (yc * WW + xc) * DD;
                v0 += tdesc[base + lane] * inb * ws4[c];
                v1 += tdesc[base + 64 + lane] * inb * ws4[c];
            } else {
                int base = yc * WW + xc;
                v0 += desc[lane * HW + base] * inb * ws4[c];
                v1 += desc[(lane + 64) * HW + base] * inb * ws4[c];
            }
        }
        float ss = v0 * v0 + v1 * v1;
        #pragma unroll
        for (int o = 32; o > 0; o >>= 1) ss += __shfl_xor(ss, o);
        if (ss == 0.0f) ss = 1.0f;   // padding lines: avoid 0/0 NaN
        float nrm = sqrtf(ss);
        ds[r][lane] = v0 / nrm;
        ds[r][64 + lane] = v1 / nrm;
        if (lane == 0) valout[pt] = (line < NLINES) ? validf : 0.0f;
    }
    __syncthreads();

    #pragma unroll
    for (int it = 0; it < 3; ++it) {
        int idx = it * 256 + t;        // 0..767 = 12 chunks x 64 lanes
        int c = idx >> 6, l = idx & 63;
        int q = l >> 4, r = l & 15;
        short8 outv;
        #pragma unroll
        for (int jj = 0; jj < 8; ++jj) {
            int kext = c * 32 + q * 8 + jj;
            int term = kext >> 7, k = kext & 127;
            float x = ds[r][k];
            __hip_bfloat16 h = __float2bfloat16(x);
            short v = *(short*)&h;
            bool lo_term = arole ? (term == 1) : (term == 2);
            if (lo_term) {
                float hf = __bfloat162float(h);
                __hip_bfloat16 lw = __float2bfloat16(x - hf);
                v = *(short*)&lw;
            }
            outv[jj] = v;
        }
        *(short8*)&Ef[((size_t)(g * NCH + c) * 64 + l) * 8] = outv;
    }
}

// ---------------- K2: MFMA score GEMM + fused per-line-pair reduction -----
// R5's double-buffered direct-global K-loop; epilogue reduces each pair
// ONCE (pass 1 -> lsc + LDS tile), pass 2 re-reads tile -> lscT coalesced.
__launch_bounds__(256, 2)
__global__ void score_kernel(const short* __restrict__ Af, const short* __restrict__ Bf,
                             const float* __restrict__ val1, const float* __restrict__ val2,
                             float* __restrict__ lsc, float* __restrict__ lscT) {
    __shared__ float dump[80 * 161];   // 51520 B
    __shared__ float red[16][33];      // 2112 B

    const int t = threadIdx.x;
    const int lane = t & 63;
    const int w = t >> 6;           // wave 0..3
    const int wm = w >> 1;          // 0..1 row half
    const int wn = w & 1;           // 0..1 col half
    const int gA0 = blockIdx.x * 10;   // first 16-pt group of A side
    const int gB0 = blockIdx.y * 10;

    const short* pa[5];
    const short* pb[5];
    #pragma unroll
    for (int ti = 0; ti < 5; ++ti) {
        pa[ti] = Af + ((size_t)(gA0 + 5 * wm + ti) * NCH * 64 + lane) * 8;
        pb[ti] = Bf + ((size_t)(gB0 + 5 * wn + ti) * NCH * 64 + lane) * 8;
    }

    f32x4 acc[5][5];
    #pragma unroll
    for (int a = 0; a < 5; ++a)
        #pragma unroll
        for (int b = 0; b < 5; ++b)
            acc[a][b] = (f32x4){0.f, 0.f, 0.f, 0.f};

    short8 ca[5], cb[5], na[5], nb[5];
    #pragma unroll
    for (int ti = 0; ti < 5; ++ti) {
        ca[ti] = *(const short8*)(pa[ti]);
        cb[ti] = *(const short8*)(pb[ti]);
    }
    #pragma unroll
    for (int c = 0; c < NCH; c += 2) {
        #pragma unroll
        for (int ti = 0; ti < 5; ++ti) {
            na[ti] = *(const short8*)(pa[ti] + (c + 1) * 512);
            nb[ti] = *(const short8*)(pb[ti] + (c + 1) * 512);
        }
        #pragma unroll
        for (int ti = 0; ti < 5; ++ti)
            #pragma unroll
            for (int tj = 0; tj < 5; ++tj)
                acc[ti][tj] = __builtin_amdgcn_mfma_f32_16x16x32_bf16(
                    ca[ti], cb[tj], acc[ti][tj], 0, 0, 0);
        if (c + 2 < NCH) {
            #pragma unroll
            for (int ti = 0; ti < 5; ++ti) {
                ca[ti] = *(const short8*)(pa[ti] + (c + 2) * 512);
                cb[ti] = *(const short8*)(pb[ti] + (c + 2) * 512);
            }
        }
        #pragma unroll
        for (int ti = 0; ti < 5; ++ti)
            #pragma unroll
            for (int tj = 0; tj < 5; ++tj)
                acc[ti][tj] = __builtin_amdgcn_mfma_f32_16x16x32_bf16(
                    na[ti], nb[tj], acc[ti][tj], 0, 0, 0);
    }

    const int i0l = blockIdx.x * 32;
    const int j0l = blockIdx.y * 32;
    #pragma unroll
    for (int p = 0; p < 2; ++p) {
        __syncthreads();
        if (wm == p) {
            #pragma unroll
            for (int ti = 0; ti < 5; ++ti) {
                #pragma unroll
                for (int reg = 0; reg < 4; ++reg) {
                    int rloc = 16 * ti + (lane >> 4) * 4 + reg;
                    #pragma unroll
                    for (int tj = 0; tj < 5; ++tj) {
                        int col = 80 * wn + 16 * tj + (lane & 15);
                        dump[rloc * 161 + col] = acc[ti][tj][reg];
                    }
                }
            }
        }
        __syncthreads();
        // pass 1: reduce once per pair, write lsc (coalesced in j), park in red
        #pragma unroll
        for (int e = 0; e < 2; ++e) {
            int q = t * 2 + e;            // 0..511
            int li = q >> 5, lj = q & 31;
            int i = i0l + 16 * p + li;
            int j = j0l + lj;
            float S[5][5];
            #pragma unroll
            for (int a = 0; a < 5; ++a) {
                float va = val1[i * NS + a];   // i < NPAD always: safe
                #pragma unroll
                for (int b = 0; b < 5; ++b) {
                    float vb = val2[j * NS + b];
                    float sc = dump[(li * 5 + a) * 161 + (lj * 5 + b)];
                    S[a][b] = (va != 0.0f && vb != 0.0f) ? sc : -1.0f;
                }
            }
            float sum1 = 0.0f, cnt1 = 0.0f;
            #pragma unroll
            for (int a = 0; a < 5; ++a) {
                float r = S[a][0];
                #pragma unroll
                for (int b = 1; b < 5; ++b) r = fmaxf(r, S[a][b]);
                float v = (r != -1.0f) ? 1.0f : 0.0f;
                sum1 += r * v; cnt1 += v;
            }
            float sum2 = 0.0f, cnt2 = 0.0f;
            #pragma unroll
            for (int b = 0; b < 5; ++b) {
                float r = S[0][b];
                #pragma unroll
                for (int a = 1; a < 5; ++a) r = fmaxf(r, S[a][b]);
                float v = (r != -1.0f) ? 1.0f : 0.0f;
                sum2 += r * v; cnt2 += v;
            }
            float res = (sum1 / cnt1 + sum2 / cnt2) * 0.5f;
            red[li][lj] = res;
            if (i < NLINES && j < NLINES) lsc[i * NLINES + j] = res;
        }
        __syncthreads();
        // pass 2: lscT from red, coalesced in i
        #pragma unroll
        for (int e = 0; e < 2; ++e) {
            int q = t + 256 * e;          // 0..511
            int li = q & 15, lj = q >> 4;
            int i = i0l + 16 * p + li;
            int j = j0l + lj;
            if (i < NLINES && j < NLINES) lscT[j * NLINES + i] = red[li][lj];
        }
    }
}

// ------- K3a: per-row top-10 both dirs (stable-argsort tie semantics) -----
__global__ void topk_kernel(const float* __restrict__ lsc, const float* __restrict__ lscT,
                            int* __restrict__ topk1, int* __restrict__ topk2) {
    __shared__ float wv[4];
    __shared__ int wi[4];
    int rb = blockIdx.x;               // 0..2399
    const float* ls = (rb < NLINES) ? (lsc + rb * NLINES) : (lscT + (rb - NLINES) * NLINES);
    int* topk = (rb < NLINES) ? (topk1 + rb * 10) : (topk2 + (rb - NLINES) * 10);
    int t = threadIdx.x;
    int lane = t & 63, w = t >> 6;
    float val[5];
    #pragma unroll
    for (int s = 0; s < 5; ++s) {
        int j = t + 256 * s;
        val[s] = (j < NLINES) ? ls[j] : -1e30f;
    }
    float bv = -1e30f; int bi = -1;
    #pragma unroll
    for (int s = 0; s < 5; ++s) {
        int j = t + 256 * s;
        if (val[s] >= bv) { bv = val[s]; bi = j; }
    }
    for (int sel = 0; sel < 10; ++sel) {
        float rv = bv; int ri = bi;
        #pragma unroll
        for (int o = 32; o > 0; o >>= 1) {
            float ov = __shfl_xor(rv, o);
            int oi = __shfl_xor(ri, o);
            if (ov > rv || (ov == rv && oi > ri)) { rv = ov; ri = oi; }
        }
        if (lane == 0) { wv[w] = rv; wi[w] = ri; }
        __syncthreads();
        float fv = wv[0]; int fi = wi[0];
        #pragma unroll
        for (int qq = 1; qq < 4; ++qq)
            if (wv[qq] > fv || (wv[qq] == fv && wi[qq] > fi)) { fv = wv[qq]; fi = wi[qq]; }
        if (t == 0) topk[9 - sel] = fi;
        if ((fi & 255) == t) {
            val[fi >> 8] = -1e30f;
            bv = -1e30f; bi = -1;
            #pragma unroll
            for (int s = 0; s < 5; ++s) {
                int j = t + 256 * s;
                if (val[s] >= bv) { bv = val[s]; bi = j; }
            }
        }
        __syncthreads();
    }
}

// ---------------- K3b: NW, one row per 320-thread block (5 waves) ---------
// Wave w computes candidates 2w, 2w+1 via one 12-chunk MFMA chain.
__device__ __forceinline__ float nw5(const float* M) {
    float F[6] = {0, 0, 0, 0, 0, 0};
    #pragma unroll
    for (int x = 0; x < 5; ++x) {
        float diag = F[0];
        float left = 0.0f;
        #pragma unroll
        for (int y = 1; y <= 5; ++y) {
            float up = F[y];
            float cur = fmaxf(fmaxf(left, up), diag + (M[x * 5 + y - 1] - GAPC));
            F[y] = cur; left = cur; diag = up;
        }
    }
    return F[5];
}

__global__ void nw_kernel(const short* __restrict__ Af, const short* __restrict__ Bf,
                          const float* __restrict__ val1, const float* __restrict__ val2,
                          const int* __restrict__ topk1, const int* __restrict__ topk2,
                          float* __restrict__ nwout, float* __restrict__ nw2buf) {
    __shared__ float sbuf[10][25];
    __shared__ int jl[10];
    int rb = blockIdx.x;                    // 0..2399
    int dir = (rb >= NLINES) ? 1 : 0;
    int row = rb - dir * NLINES;
    int t = threadIdx.x;                    // 0..319
    int w = t >> 6;                         // wave = candidate pair 0..4
    int lane = t & 63;
    int q = lane >> 4, rr = lane & 15;

    if (t < 10) jl[t] = (dir ? topk2 : topk1)[row * 10 + t];
    __syncthreads();

    const short* shEf = dir ? Bf : Af;      // shared side
    const short* cdEf = dir ? Af : Bf;      // candidate side

    int ptS = row * 5 + min(rr, 4);
    const short* shp = shEf + ((size_t)(ptS >> 4) * NCH * 64 + q * 16 + (ptS & 15)) * 8;

    int c1 = jl[2 * w], c2 = jl[2 * w + 1];
    int ptC = (rr < 8) ? (c1 * 5 + min(rr, 4)) : (c2 * 5 + min(rr - 8, 4));
    const short* cp = cdEf + ((size_t)(ptC >> 4) * NCH * 64 + q * 16 + (ptC & 15)) * 8;

    f32x4 acc = (f32x4){0.f, 0.f, 0.f, 0.f};
    #pragma unroll
    for (int c = 0; c < NCH; ++c) {
        short8 sh = *(const short8*)(shp + c * 512);
        short8 cb = *(const short8*)(cp + c * 512);
        acc = dir ? __builtin_amdgcn_mfma_f32_16x16x32_bf16(cb, sh, acc, 0, 0, 0)
                  : __builtin_amdgcn_mfma_f32_16x16x32_bf16(sh, cb, acc, 0, 0, 0);
    }
    // C layout: m = q*4+reg, n = lane&15
    #pragma unroll
    for (int reg = 0; reg < 4; ++reg) {
        int m = q * 4 + reg, n = rr;
        if (!dir) {
            if (m < 5 && n < 5) sbuf[2 * w][m * 5 + n] = acc[reg];
            if (m < 5 && n >= 8 && n < 13) sbuf[2 * w + 1][m * 5 + (n - 8)] = acc[reg];
        } else {
            if (m < 5 && n < 5) sbuf[2 * w][m * 5 + n] = acc[reg];
            if (m >= 8 && m < 13 && n < 5) sbuf[2 * w + 1][(m - 8) * 5 + n] = acc[reg];
        }
    }
    __syncthreads();

    if (t < 20) {
        int r = t >> 1, rev = t & 1;
        int i = dir ? jl[r] : row;
        int j = dir ? row : jl[r];
        float S[25];
        #pragma unroll
        for (int a = 0; a < 5; ++a) {
            float va = val1[i * NS + a];
            #pragma unroll
            for (int b = 0; b < 5; ++b) {
                float vb = val2[j * NS + b];
                S[a * 5 + b] = (va != 0.0f && vb != 0.0f) ? sbuf[r][a * 5 + b] : -1.0f;
            }
        }
        float M[25];
        #pragma unroll
        for (int x = 0; x < 5; ++x)
            #pragma unroll
            for (int y = 0; y < 5; ++y) {
                if (!dir) M[x * 5 + y] = rev ? S[x * 5 + (4 - y)] : S[x * 5 + y];
                else      M[x * 5 + y] = rev ? S[(4 - y) * 5 + x] : S[y * 5 + x];
            }
        float nwv = nw5(M);
        float* o = dir ? nw2buf : nwout;
        o[row * 20 + rev * 10 + r] = nwv;
    }
}

// ---------------- K3c: argmax over 20 + mutual check (single block) -------
__global__ void argmax_final_kernel(const float* __restrict__ nw1, const float* __restrict__ nw2,
                                    const int* __restrict__ topk1, const int* __restrict__ topk2,
                                    float* __restrict__ out) {
    __shared__ int mpre[NLINES];
    __shared__ int m2[NLINES];
    int t = threadIdx.x;               // 0..1023
    for (int qq = t; qq < 2 * NLINES; qq += 1024) {
        int dir = qq / NLINES, row = qq - dir * NLINES;
        const float* nw = (dir ? nw2 : nw1) + row * 20;
        float best = nw[0]; int bi = 0;
        #pragma unroll
        for (int q = 1; q < 20; ++q) {
            float v = nw[q];
            if (v > best) { best = v; bi = q; }
        }
        int m = (dir ? topk2 : topk1)[row * 10 + (bi % 10)];
        if (dir) m2[row] = m; else mpre[row] = m;
    }
    __syncthreads();
    for (int i = t; i < NLINES; i += 1024) {
        int m = mpre[i];
        out[i] = (m2[m] == i) ? (float)m : -1.0f;
    }
}

extern "C" void kernel_launch(void* const* d_in, const int* in_sizes, int n_in,
                              void* d_out, int out_size, void* d_ws, size_t ws_size,
                              hipStream_t stream) {
    const float* lseg1 = (const float*)d_in[0];
    const float* lseg2 = (const float*)d_in[1];
    const float* desc1 = (const float*)d_in[2];
    const float* desc2 = (const float*)d_in[3];
    float* out = (float*)d_out;

    float* wsf = (float*)d_ws;
    size_t off = 0;
    float* val1 = wsf + off;   off += PPAD;
    float* val2 = wsf + off;   off += PPAD;
    float* lsc = wsf + off;    off += (size_t)NLINES * NLINES;
    float* lscT = wsf + off;   off += (size_t)NLINES * NLINES;
    int* topk1 = (int*)(wsf + off); off += NLINES * 10;
    int* topk2 = (int*)(wsf + off); off += NLINES * 10;
    float* nw2buf = wsf + off; off += NLINES * 20;
    short* Aext = (short*)(wsf + off); off += (size_t)PPAD * KEXT / 2;
    short* Bext = (short*)(wsf + off); off += (size_t)PPAD * KEXT / 2;
    float* tdesc1 = wsf + off; off += (size_t)HW * DD;
    float* tdesc2 = wsf + off; off += (size_t)HW * DD;
    size_t need_full = off * sizeof(float);
    int use_t = (ws_size >= need_full) ? 1 : 0;

    if (use_t) {
        transpose_desc<<<dim3(HW / 128, DD / 32, 2), 256, 0, stream>>>(
            desc1, tdesc1, desc2, tdesc2);
    }
    samplepack_kernel<<<dim3(NGRP, 2), 256, 0, stream>>>(
        lseg1, lseg2, tdesc1, tdesc2, desc1, desc2, Aext, Bext, val1, val2, use_t);

    score_kernel<<<dim3(NPAD / 32, NPAD / 32), 256, 0, stream>>>(Aext, Bext, val1, val2,
                                                                 lsc, lscT);

    topk_kernel<<<2 * NLINES, 256, 0, stream>>>(lsc, lscT, topk1, topk2);

    nw_kernel<<<2 * NLINES, 320, 0, stream>>>(Aext, Bext, val1, val2, topk1, topk2,
                                              out + NLINES, nw2buf);

    argmax_final_kernel<<<1, 1024, 0, stream>>>(out + NLINES, nw2buf, topk1, topk2, out);
}